// Round 1
// baseline (517.853 us; speedup 1.0000x reference)
//
#include <hip/hip_runtime.h>

#define B_   8
#define C_   128
#define N_   4096
#define C2_  64

typedef __bf16 bf16x8 __attribute__((ext_vector_type(8)));
typedef float  f32x4  __attribute__((ext_vector_type(4)));

#define MFMA16(a, b, c) __builtin_amdgcn_mfma_f32_16x16x32_bf16((a), (b), (c), 0, 0, 0)

// sqrt(log2(e)): fold into q/k so softmax uses exp2 directly (E' = E * log2e)
#define QK_SCALE 1.2011224087864498f

static __device__ __forceinline__ unsigned short f2bf(float f) {
    union { __bf16 b; unsigned short u; } cv;
    cv.b = (__bf16)f;
    return cv.u;
}

struct us4 { unsigned short a, b, c, d; };

// ---------------------------------------------------------------------------
// K1: projections.  qk_t[b][n][o] (bf16, pre-scaled), xv_bf[b][o][n] (bf16, +b_v),
//     xc[b][o][n] (f32).  Wave handles 1 output channel o x 256 n (float4 x-loads).
// ---------------------------------------------------------------------------
__global__ __launch_bounds__(256) void k1_proj(
    const float* __restrict__ x, const float* __restrict__ w_qk,
    const float* __restrict__ w_v, const float* __restrict__ b_v,
    const float* __restrict__ w_x,
    unsigned short* __restrict__ qk_t, unsigned short* __restrict__ xv_bf,
    float* __restrict__ xc)
{
    const int wave = threadIdx.x >> 6, lane = threadIdx.x & 63;
    const int b = blockIdx.y;
    const int n_base = blockIdx.x * 256;
    const int o = blockIdx.z * 4 + wave;
    const int n = n_base + lane * 4;

    const float* xb = x + (size_t)b * C_ * N_ + n;
    float aq[4] = {0.f, 0.f, 0.f, 0.f};
    float av[4] = {0.f, 0.f, 0.f, 0.f};
    float ax[4] = {0.f, 0.f, 0.f, 0.f};

    for (int c = 0; c < C_; ++c) {
        const float4 xv4 = *(const float4*)(xb + (size_t)c * N_);
        const float wq = w_qk[o * C_ + c];
        const float wv = w_v[o * C_ + c];
        const float wx = w_x[o * C_ + c];
        aq[0] += wq * xv4.x; aq[1] += wq * xv4.y; aq[2] += wq * xv4.z; aq[3] += wq * xv4.w;
        av[0] += wv * xv4.x; av[1] += wv * xv4.y; av[2] += wv * xv4.z; av[3] += wv * xv4.w;
        ax[0] += wx * xv4.x; ax[1] += wx * xv4.y; ax[2] += wx * xv4.z; ax[3] += wx * xv4.w;
    }
    const float bv = b_v[o];

    // qk_t: [b][n][o] scattered bf16 stores (stride C2_)
    #pragma unroll
    for (int j = 0; j < 4; ++j)
        qk_t[(size_t)(b * N_ + n + j) * C2_ + o] = f2bf(aq[j] * QK_SCALE);

    us4 sv;
    sv.a = f2bf(av[0] + bv); sv.b = f2bf(av[1] + bv);
    sv.c = f2bf(av[2] + bv); sv.d = f2bf(av[3] + bv);
    *(us4*)(xv_bf + (size_t)(b * C2_ + o) * N_ + n) = sv;

    float4 cv4;
    cv4.x = ax[0]; cv4.y = ax[1]; cv4.z = ax[2]; cv4.w = ax[3];
    *(float4*)(xc + (size_t)(b * C2_ + o) * N_ + n) = cv4;
}

// ---------------------------------------------------------------------------
// K2: row softmax stats (base-2 domain).  rowoff[b][n] = rowmax + log2(rowsum).
//     Wave owns 16 rows; streams all m in 64-wide tiles via MFMA.
// ---------------------------------------------------------------------------
__global__ __launch_bounds__(256) void k2_rowstats(
    const unsigned short* __restrict__ qk_t, float* __restrict__ rowoff)
{
    const int wave = threadIdx.x >> 6, lane = threadIdx.x & 63;
    const int quad = lane >> 4, col = lane & 15;
    const int b = blockIdx.y;
    const int n_base = blockIdx.x * 64 + wave * 16;
    const unsigned short* qb = qk_t + (size_t)b * N_ * C2_;

    const bf16x8 a0 = *(const bf16x8*)(qb + (n_base + col) * C2_ + quad * 8);
    const bf16x8 a1 = *(const bf16x8*)(qb + (n_base + col) * C2_ + quad * 8 + 32);

    float run_m[4] = {-1e30f, -1e30f, -1e30f, -1e30f};
    float run_s[4] = {0.f, 0.f, 0.f, 0.f};

    for (int mt = 0; mt < N_; mt += 64) {
        f32x4 e[4];
        #pragma unroll
        for (int ms = 0; ms < 4; ++ms) {
            const int m = mt + ms * 16;
            const bf16x8 b0 = *(const bf16x8*)(qb + (m + col) * C2_ + quad * 8);
            const bf16x8 b1 = *(const bf16x8*)(qb + (m + col) * C2_ + quad * 8 + 32);
            f32x4 acc = {0.f, 0.f, 0.f, 0.f};
            acc = MFMA16(a0, b0, acc);
            acc = MFMA16(a1, b1, acc);
            e[ms] = acc;
        }
        #pragma unroll
        for (int r = 0; r < 4; ++r) {
            float lm = fmaxf(fmaxf(e[0][r], e[1][r]), fmaxf(e[2][r], e[3][r]));
            #pragma unroll
            for (int off = 1; off < 16; off <<= 1)
                lm = fmaxf(lm, __shfl_xor(lm, off, 64));
            float ls = exp2f(e[0][r] - lm) + exp2f(e[1][r] - lm) +
                       exp2f(e[2][r] - lm) + exp2f(e[3][r] - lm);
            #pragma unroll
            for (int off = 1; off < 16; off <<= 1)
                ls += __shfl_xor(ls, off, 64);
            const float nm = fmaxf(run_m[r], lm);
            run_s[r] = run_s[r] * exp2f(run_m[r] - nm) + ls * exp2f(lm - nm);
            run_m[r] = nm;
        }
    }

    if (col == 0) {
        #pragma unroll
        for (int r = 0; r < 4; ++r)
            rowoff[b * N_ + n_base + quad * 4 + r] = run_m[r] + log2f(run_s[r]);
    }
}

// ---------------------------------------------------------------------------
// K3: recompute E per m-tile, S = exp2(E - off), accumulate Y = xv*S via MFMA
//     and colsum; write x_r = Y / (1e-9 + colsum).  Wave owns 16 m-cols.
//     S goes C-layout -> LDS (padded stride 40) -> B-operand ds_read_b128.
// ---------------------------------------------------------------------------
__global__ __launch_bounds__(256) void k3_pv(
    const unsigned short* __restrict__ qk_t, const unsigned short* __restrict__ xv_bf,
    const float* __restrict__ rowoff, float* __restrict__ xr)
{
    __shared__ unsigned short stile[4][16][40];
    const int wave = threadIdx.x >> 6, lane = threadIdx.x & 63;
    const int quad = lane >> 4, col = lane & 15;
    const int b = blockIdx.y;
    const int m_base = blockIdx.x * 64 + wave * 16;
    const unsigned short* qb = qk_t + (size_t)b * N_ * C2_;
    const unsigned short* vb = xv_bf + (size_t)b * C2_ * N_;
    const float* ro = rowoff + b * N_;

    const bf16x8 kb0 = *(const bf16x8*)(qb + (m_base + col) * C2_ + quad * 8);
    const bf16x8 kb1 = *(const bf16x8*)(qb + (m_base + col) * C2_ + quad * 8 + 32);

    f32x4 accY[4];
    #pragma unroll
    for (int os = 0; os < 4; ++os) accY[os] = (f32x4){0.f, 0.f, 0.f, 0.f};
    float colacc = 0.f;
    unsigned short (*st)[40] = stile[wave];

    for (int n0 = 0; n0 < N_; n0 += 32) {
        f32x4 e[2];
        #pragma unroll
        for (int ns = 0; ns < 2; ++ns) {
            const bf16x8 qa0 = *(const bf16x8*)(qb + (n0 + ns * 16 + col) * C2_ + quad * 8);
            const bf16x8 qa1 = *(const bf16x8*)(qb + (n0 + ns * 16 + col) * C2_ + quad * 8 + 32);
            f32x4 acc = {0.f, 0.f, 0.f, 0.f};
            acc = MFMA16(qa0, kb0, acc);
            acc = MFMA16(qa1, kb1, acc);
            e[ns] = acc;
        }
        #pragma unroll
        for (int ns = 0; ns < 2; ++ns) {
            union { unsigned short us[4]; uint2 u2; } p;
            #pragma unroll
            for (int r = 0; r < 4; ++r) {
                const float off = ro[n0 + ns * 16 + quad * 4 + r];
                const float s = exp2f(e[ns][r] - off);
                colacc += s;
                p.us[r] = f2bf(s);
            }
            *(uint2*)&st[col][ns * 16 + quad * 4] = p.u2;
        }
        // same-wave LDS round-trip (lockstep; no barrier needed)
        const bf16x8 sB = *(const bf16x8*)&st[col][quad * 8];
        #pragma unroll
        for (int os = 0; os < 4; ++os) {
            const bf16x8 va = *(const bf16x8*)(vb + (size_t)(os * 16 + col) * N_ + n0 + quad * 8);
            accY[os] = MFMA16(va, sB, accY[os]);
        }
    }

    colacc += __shfl_xor(colacc, 16, 64);
    colacc += __shfl_xor(colacc, 32, 64);
    const float inv = 1.f / (1e-9f + colacc);

    #pragma unroll
    for (int os = 0; os < 4; ++os)
        #pragma unroll
        for (int r = 0; r < 4; ++r)
            xr[(size_t)(b * C2_ + os * 16 + quad * 4 + r) * N_ + m_base + col] = accY[os][r] * inv;
}

// ---------------------------------------------------------------------------
// K4: t = w_t @ (xc - xr) + b_t, per (b, 64-n tile).  d-tile + w_t in LDS.
// ---------------------------------------------------------------------------
__global__ __launch_bounds__(256) void k4_t(
    const float* __restrict__ xc, const float* __restrict__ xr,
    const float* __restrict__ w_t, const float* __restrict__ b_t,
    float* __restrict__ t_buf)
{
    __shared__ float d_lds[64][64];
    __shared__ float w_lds[64][64];
    const int b = blockIdx.y;
    const int n0 = blockIdx.x * 64;
    const size_t base = (size_t)b * C2_ * N_;

    for (int idx = threadIdx.x; idx < 4096; idx += 256) {
        const int i = idx >> 6, n = idx & 63;
        const size_t g = base + (size_t)i * N_ + n0 + n;
        d_lds[i][n] = xc[g] - xr[g];
        w_lds[i][n] = w_t[idx];   // w_lds[o][i]
    }
    __syncthreads();

    const int n = threadIdx.x & 63, ow = (threadIdx.x >> 6) * 16;
    float acc[16];
    #pragma unroll
    for (int oo = 0; oo < 16; ++oo) acc[oo] = 0.f;
    for (int i = 0; i < 64; ++i) {
        const float dv = d_lds[i][n];
        #pragma unroll
        for (int oo = 0; oo < 16; ++oo)
            acc[oo] += w_lds[ow + oo][i] * dv;
    }
    #pragma unroll
    for (int oo = 0; oo < 16; ++oo)
        t_buf[base + (size_t)(ow + oo) * N_ + n0 + n] = acc[oo] + b_t[ow + oo];
}

// ---------------------------------------------------------------------------
// K5: BN batch stats per channel (sum, sumsq over B*N).  One block per o.
// ---------------------------------------------------------------------------
__global__ __launch_bounds__(256) void k5_bnstats(
    const float* __restrict__ t_buf, float* __restrict__ bn)
{
    const int o = blockIdx.x;
    float s = 0.f, s2 = 0.f;
    for (int b = 0; b < B_; ++b) {
        const float4* p = (const float4*)(t_buf + (size_t)(b * C2_ + o) * N_);
        for (int j = threadIdx.x; j < N_ / 4; j += 256) {
            const float4 v = p[j];
            s  += v.x + v.y + v.z + v.w;
            s2 += v.x * v.x + v.y * v.y + v.z * v.z + v.w * v.w;
        }
    }
    #pragma unroll
    for (int off = 1; off < 64; off <<= 1) {
        s  += __shfl_xor(s, off, 64);
        s2 += __shfl_xor(s2, off, 64);
    }
    __shared__ float red[2][4];
    if ((threadIdx.x & 63) == 0) {
        red[0][threadIdx.x >> 6] = s;
        red[1][threadIdx.x >> 6] = s2;
    }
    __syncthreads();
    if (threadIdx.x == 0) {
        bn[o]       = red[0][0] + red[0][1] + red[0][2] + red[0][3];
        bn[64 + o]  = red[1][0] + red[1][1] + red[1][2] + red[1][3];
    }
}

// ---------------------------------------------------------------------------
// K6: out = xc + relu(gamma * (t - mean) * rsqrt(var + eps) + beta)
// ---------------------------------------------------------------------------
__global__ __launch_bounds__(256) void k6_out(
    const float* __restrict__ xc, const float* __restrict__ t_buf,
    const float* __restrict__ bn, const float* __restrict__ gamma,
    const float* __restrict__ beta, float* __restrict__ out)
{
    const int idx = blockIdx.x * 256 + threadIdx.x;   // float4 index
    const int o = (idx >> 10) & 63;                    // 1024 float4 per row
    const float invC = 1.0f / (float)(B_ * N_);
    const float mean = bn[o] * invC;
    const float var  = bn[64 + o] * invC - mean * mean;
    const float sc = gamma[o] * rsqrtf(var + 1e-5f);
    const float sh = beta[o] - mean * sc;
    const float4 t4 = ((const float4*)t_buf)[idx];
    const float4 c4 = ((const float4*)xc)[idx];
    float4 r;
    r.x = c4.x + fmaxf(0.f, sc * t4.x + sh);
    r.y = c4.y + fmaxf(0.f, sc * t4.y + sh);
    r.z = c4.z + fmaxf(0.f, sc * t4.z + sh);
    r.w = c4.w + fmaxf(0.f, sc * t4.w + sh);
    ((float4*)out)[idx] = r;
}

extern "C" void kernel_launch(void* const* d_in, const int* in_sizes, int n_in,
                              void* d_out, int out_size, void* d_ws, size_t ws_size,
                              hipStream_t stream) {
    const float* x     = (const float*)d_in[0];
    const float* w_qk  = (const float*)d_in[1];
    const float* w_v   = (const float*)d_in[2];
    const float* b_v   = (const float*)d_in[3];
    const float* w_x   = (const float*)d_in[4];
    const float* w_t   = (const float*)d_in[5];
    const float* b_t   = (const float*)d_in[6];
    const float* gamma = (const float*)d_in[7];
    const float* beta  = (const float*)d_in[8];
    float* out = (float*)d_out;

    char* ws = (char*)d_ws;
    unsigned short* qk_t  = (unsigned short*)ws;                 // 4 MB
    unsigned short* xv_bf = (unsigned short*)(ws + (4  << 20));  // 4 MB
    float* xc     = (float*)(ws + (8  << 20));                   // 8 MB
    float* xr     = (float*)(ws + (16 << 20));                   // 8 MB
    float* tbuf   = (float*)(ws + (24 << 20));                   // 8 MB
    float* rowoff = (float*)(ws + (32 << 20));                   // 128 KB
    float* bn     = (float*)(ws + (32 << 20) + (1 << 19));       // 512 B

    hipLaunchKernelGGL(k1_proj,     dim3(16, 8, 16), 256, 0, stream,
                       x, w_qk, w_v, b_v, w_x, qk_t, xv_bf, xc);
    hipLaunchKernelGGL(k2_rowstats, dim3(64, 8),     256, 0, stream, qk_t, rowoff);
    hipLaunchKernelGGL(k3_pv,       dim3(64, 8),     256, 0, stream, qk_t, xv_bf, rowoff, xr);
    hipLaunchKernelGGL(k4_t,        dim3(64, 8),     256, 0, stream, xc, xr, w_t, b_t, tbuf);
    hipLaunchKernelGGL(k5_bnstats,  dim3(64),        256, 0, stream, tbuf, bn);
    hipLaunchKernelGGL(k6_out,      dim3(2048),      256, 0, stream, xc, tbuf, bn, gamma, beta, out);
}

// Round 2
// 517.142 us; speedup vs baseline: 1.0014x; 1.0014x over previous
//
#include <hip/hip_runtime.h>

#define B_   8
#define C_   128
#define N_   4096
#define C2_  64

typedef __bf16 bf16x8 __attribute__((ext_vector_type(8)));
typedef float  f32x4  __attribute__((ext_vector_type(4)));

#define MFMA16(a, b, c) __builtin_amdgcn_mfma_f32_16x16x32_bf16((a), (b), (c), 0, 0, 0)

// sqrt(log2(e)): fold into q/k so softmax uses exp2 directly (E' = E * log2e)
#define QK_SCALE 1.2011224087864498f

static __device__ __forceinline__ unsigned short f2bf(float f) {
    union { __bf16 b; unsigned short u; } cv;
    cv.b = (__bf16)f;
    return cv.u;
}

struct us4 { unsigned short a, b, c, d; };

// 4 row-subtile A/B fragments (rows r_base + ns*16 + col, both 32-K halves)
struct Frag4 { bf16x8 h0[4], h1[4]; };

static __device__ __forceinline__ void load_frag4(
    const unsigned short* __restrict__ qb, int r_base, int col, int quad, Frag4& R)
{
    #pragma unroll
    for (int ns = 0; ns < 4; ++ns) {
        const unsigned short* p = qb + (size_t)(r_base + ns * 16 + col) * C2_ + quad * 8;
        R.h0[ns] = *(const bf16x8*)p;
        R.h1[ns] = *(const bf16x8*)(p + 32);
    }
}

// ---------------------------------------------------------------------------
// K1: projections.  qk_t[b][n][o] (bf16, pre-scaled), xv_bf[b][o][n] (bf16, +b_v),
//     xc[b][o][n] (f32).  Wave handles 1 output channel o x 256 n (float4 x-loads).
// ---------------------------------------------------------------------------
__global__ __launch_bounds__(256) void k1_proj(
    const float* __restrict__ x, const float* __restrict__ w_qk,
    const float* __restrict__ w_v, const float* __restrict__ b_v,
    const float* __restrict__ w_x,
    unsigned short* __restrict__ qk_t, unsigned short* __restrict__ xv_bf,
    float* __restrict__ xc)
{
    const int wave = threadIdx.x >> 6, lane = threadIdx.x & 63;
    const int b = blockIdx.y;
    const int n_base = blockIdx.x * 256;
    const int o = blockIdx.z * 4 + wave;
    const int n = n_base + lane * 4;

    const float* xb = x + (size_t)b * C_ * N_ + n;
    float aq[4] = {0.f, 0.f, 0.f, 0.f};
    float av[4] = {0.f, 0.f, 0.f, 0.f};
    float ax[4] = {0.f, 0.f, 0.f, 0.f};

    for (int c = 0; c < C_; ++c) {
        const float4 xv4 = *(const float4*)(xb + (size_t)c * N_);
        const float wq = w_qk[o * C_ + c];
        const float wv = w_v[o * C_ + c];
        const float wx = w_x[o * C_ + c];
        aq[0] += wq * xv4.x; aq[1] += wq * xv4.y; aq[2] += wq * xv4.z; aq[3] += wq * xv4.w;
        av[0] += wv * xv4.x; av[1] += wv * xv4.y; av[2] += wv * xv4.z; av[3] += wv * xv4.w;
        ax[0] += wx * xv4.x; ax[1] += wx * xv4.y; ax[2] += wx * xv4.z; ax[3] += wx * xv4.w;
    }
    const float bv = b_v[o];

    // qk_t: [b][n][o] scattered bf16 stores (stride C2_)
    #pragma unroll
    for (int j = 0; j < 4; ++j)
        qk_t[(size_t)(b * N_ + n + j) * C2_ + o] = f2bf(aq[j] * QK_SCALE);

    us4 sv;
    sv.a = f2bf(av[0] + bv); sv.b = f2bf(av[1] + bv);
    sv.c = f2bf(av[2] + bv); sv.d = f2bf(av[3] + bv);
    *(us4*)(xv_bf + (size_t)(b * C2_ + o) * N_ + n) = sv;

    float4 cv4;
    cv4.x = ax[0]; cv4.y = ax[1]; cv4.z = ax[2]; cv4.w = ax[3];
    *(float4*)(xc + (size_t)(b * C2_ + o) * N_ + n) = cv4;
}

// ---------------------------------------------------------------------------
// K2: row softmax stats.  rowoff[b][n] = log2(sum_m 2^E[n][m]).
//     No in-loop reductions: per-lane raw exp2 accumulation (|E'| <= ~60,
//     fp32 cannot overflow), single cross-lane reduce at the end.
//     Prefetched B-fragments, m-step 128 (2 chunks).  Grid 512 1-D, b = id&7.
// ---------------------------------------------------------------------------
__global__ __launch_bounds__(256) void k2_rowstats(
    const unsigned short* __restrict__ qk_t, float* __restrict__ rowoff)
{
    const int wave = threadIdx.x >> 6, lane = threadIdx.x & 63;
    const int quad = lane >> 4, col = lane & 15;
    const int b = blockIdx.x & 7;
    const int n_base = (blockIdx.x >> 3) * 64 + wave * 16;
    const unsigned short* qb = qk_t + (size_t)b * N_ * C2_;

    const bf16x8 a0 = *(const bf16x8*)(qb + (n_base + col) * C2_ + quad * 8);
    const bf16x8 a1 = *(const bf16x8*)(qb + (n_base + col) * C2_ + quad * 8 + 32);

    float run_s[4] = {0.f, 0.f, 0.f, 0.f};
    Frag4 RA, RB;
    load_frag4(qb, 0, col, quad, RA);

    for (int mt = 0; mt < N_; mt += 128) {
        load_frag4(qb, mt + 64, col, quad, RB);
        #pragma unroll
        for (int ms = 0; ms < 4; ++ms) {
            f32x4 acc = {0.f, 0.f, 0.f, 0.f};
            acc = MFMA16(a0, RA.h0[ms], acc);
            acc = MFMA16(a1, RA.h1[ms], acc);
            #pragma unroll
            for (int r = 0; r < 4; ++r)
                run_s[r] += __builtin_amdgcn_exp2f(acc[r]);
        }
        if (mt + 128 < N_) load_frag4(qb, mt + 128, col, quad, RA);
        #pragma unroll
        for (int ms = 0; ms < 4; ++ms) {
            f32x4 acc = {0.f, 0.f, 0.f, 0.f};
            acc = MFMA16(a0, RB.h0[ms], acc);
            acc = MFMA16(a1, RB.h1[ms], acc);
            #pragma unroll
            for (int r = 0; r < 4; ++r)
                run_s[r] += __builtin_amdgcn_exp2f(acc[r]);
        }
    }

    // reduce across the 16 cols within each quad group
    #pragma unroll
    for (int r = 0; r < 4; ++r) {
        #pragma unroll
        for (int off = 1; off < 16; off <<= 1)
            run_s[r] += __shfl_xor(run_s[r], off, 64);
    }
    if (col == 0) {
        #pragma unroll
        for (int r = 0; r < 4; ++r)
            rowoff[b * N_ + n_base + quad * 4 + r] = __builtin_amdgcn_logf(run_s[r]);
    }
}

// ---------------------------------------------------------------------------
// K3: recompute E per 64-n chunk, S = exp2(E - off), Y += xv*S via MFMA,
//     colsum; x_r = Y / (1e-9 + colsum).  Ping-pong LDS S-tiles (breaks the
//     WAR serialization between chunks) + software-prefetched qa fragments.
//     Grid 512 1-D, b = id&7 (XCD-local L2 working set).
// ---------------------------------------------------------------------------
static __device__ __forceinline__ void chunk_pv(
    const Frag4& RQ, const unsigned short* __restrict__ vb,
    const float* __restrict__ ro, int n0, int col, int quad,
    const bf16x8 kb0, const bf16x8 kb1,
    unsigned short (*st)[72], f32x4 accY[4], float& colacc)
{
    // issue all independent global loads first (latency hides under E phase)
    bf16x8 va0[4], va1[4];
    #pragma unroll
    for (int os = 0; os < 4; ++os) {
        const unsigned short* p = vb + (size_t)(os * 16 + col) * N_ + n0 + quad * 8;
        va0[os] = *(const bf16x8*)p;
        va1[os] = *(const bf16x8*)(p + 32);
    }
    float4 ro4[4];
    #pragma unroll
    for (int ns = 0; ns < 4; ++ns)
        ro4[ns] = *(const float4*)(ro + n0 + ns * 16 + quad * 4);

    #pragma unroll
    for (int ns = 0; ns < 4; ++ns) {
        f32x4 acc = {0.f, 0.f, 0.f, 0.f};
        acc = MFMA16(RQ.h0[ns], kb0, acc);
        acc = MFMA16(RQ.h1[ns], kb1, acc);
        union { unsigned short us[4]; uint2 u2; } p;
        const float* rr = (const float*)&ro4[ns];
        #pragma unroll
        for (int r = 0; r < 4; ++r) {
            const float s = __builtin_amdgcn_exp2f(acc[r] - rr[r]);
            colacc += s;
            p.us[r] = f2bf(s);
        }
        *(uint2*)&st[col][ns * 16 + quad * 4] = p.u2;
    }
    // same-wave LDS round-trip (lockstep; compiler orders via lgkmcnt)
    const bf16x8 sB0 = *(const bf16x8*)&st[col][quad * 8];
    const bf16x8 sB1 = *(const bf16x8*)&st[col][32 + quad * 8];
    #pragma unroll
    for (int os = 0; os < 4; ++os) {
        accY[os] = MFMA16(va0[os], sB0, accY[os]);
        accY[os] = MFMA16(va1[os], sB1, accY[os]);
    }
}

__global__ __launch_bounds__(256) void k3_pv(
    const unsigned short* __restrict__ qk_t, const unsigned short* __restrict__ xv_bf,
    const float* __restrict__ rowoff, float* __restrict__ xr)
{
    __shared__ unsigned short stile[2][4][16][72];   // ping-pong, per-wave slices
    const int wave = threadIdx.x >> 6, lane = threadIdx.x & 63;
    const int quad = lane >> 4, col = lane & 15;
    const int b = blockIdx.x & 7;
    const int m_base = (blockIdx.x >> 3) * 64 + wave * 16;
    const unsigned short* qb = qk_t + (size_t)b * N_ * C2_;
    const unsigned short* vb = xv_bf + (size_t)b * C2_ * N_;
    const float* ro = rowoff + b * N_;

    const bf16x8 kb0 = *(const bf16x8*)(qb + (m_base + col) * C2_ + quad * 8);
    const bf16x8 kb1 = *(const bf16x8*)(qb + (m_base + col) * C2_ + quad * 8 + 32);

    f32x4 accY[4];
    #pragma unroll
    for (int os = 0; os < 4; ++os) accY[os] = (f32x4){0.f, 0.f, 0.f, 0.f};
    float colacc = 0.f;

    Frag4 RA, RB;
    load_frag4(qb, 0, col, quad, RA);

    for (int n0 = 0; n0 < N_; n0 += 128) {
        load_frag4(qb, n0 + 64, col, quad, RB);
        chunk_pv(RA, vb, ro, n0, col, quad, kb0, kb1, stile[0][wave], accY, colacc);
        if (n0 + 128 < N_) load_frag4(qb, n0 + 128, col, quad, RA);
        chunk_pv(RB, vb, ro, n0 + 64, col, quad, kb0, kb1, stile[1][wave], accY, colacc);
    }

    colacc += __shfl_xor(colacc, 16, 64);
    colacc += __shfl_xor(colacc, 32, 64);
    const float inv = 1.f / (1e-9f + colacc);

    #pragma unroll
    for (int os = 0; os < 4; ++os)
        #pragma unroll
        for (int r = 0; r < 4; ++r)
            xr[(size_t)(b * C2_ + os * 16 + quad * 4 + r) * N_ + m_base + col] = accY[os][r] * inv;
}

// ---------------------------------------------------------------------------
// K4: t = w_t @ (xc - xr) + b_t, per (b, 64-n tile).  d-tile + w_t in LDS.
// ---------------------------------------------------------------------------
__global__ __launch_bounds__(256) void k4_t(
    const float* __restrict__ xc, const float* __restrict__ xr,
    const float* __restrict__ w_t, const float* __restrict__ b_t,
    float* __restrict__ t_buf)
{
    __shared__ float d_lds[64][64];
    __shared__ float w_lds[64][64];
    const int b = blockIdx.y;
    const int n0 = blockIdx.x * 64;
    const size_t base = (size_t)b * C2_ * N_;

    for (int idx = threadIdx.x; idx < 4096; idx += 256) {
        const int i = idx >> 6, n = idx & 63;
        const size_t g = base + (size_t)i * N_ + n0 + n;
        d_lds[i][n] = xc[g] - xr[g];
        w_lds[i][n] = w_t[idx];   // w_lds[o][i]
    }
    __syncthreads();

    const int n = threadIdx.x & 63, ow = (threadIdx.x >> 6) * 16;
    float acc[16];
    #pragma unroll
    for (int oo = 0; oo < 16; ++oo) acc[oo] = 0.f;
    for (int i = 0; i < 64; ++i) {
        const float dv = d_lds[i][n];
        #pragma unroll
        for (int oo = 0; oo < 16; ++oo)
            acc[oo] += w_lds[ow + oo][i] * dv;
    }
    #pragma unroll
    for (int oo = 0; oo < 16; ++oo)
        t_buf[base + (size_t)(ow + oo) * N_ + n0 + n] = acc[oo] + b_t[ow + oo];
}

// ---------------------------------------------------------------------------
// K5: BN batch stats per channel (sum, sumsq over B*N).  One block per o.
// ---------------------------------------------------------------------------
__global__ __launch_bounds__(256) void k5_bnstats(
    const float* __restrict__ t_buf, float* __restrict__ bn)
{
    const int o = blockIdx.x;
    float s = 0.f, s2 = 0.f;
    for (int b = 0; b < B_; ++b) {
        const float4* p = (const float4*)(t_buf + (size_t)(b * C2_ + o) * N_);
        for (int j = threadIdx.x; j < N_ / 4; j += 256) {
            const float4 v = p[j];
            s  += v.x + v.y + v.z + v.w;
            s2 += v.x * v.x + v.y * v.y + v.z * v.z + v.w * v.w;
        }
    }
    #pragma unroll
    for (int off = 1; off < 64; off <<= 1) {
        s  += __shfl_xor(s, off, 64);
        s2 += __shfl_xor(s2, off, 64);
    }
    __shared__ float red[2][4];
    if ((threadIdx.x & 63) == 0) {
        red[0][threadIdx.x >> 6] = s;
        red[1][threadIdx.x >> 6] = s2;
    }
    __syncthreads();
    if (threadIdx.x == 0) {
        bn[o]       = red[0][0] + red[0][1] + red[0][2] + red[0][3];
        bn[64 + o]  = red[1][0] + red[1][1] + red[1][2] + red[1][3];
    }
}

// ---------------------------------------------------------------------------
// K6: out = xc + relu(gamma * (t - mean) * rsqrt(var + eps) + beta)
// ---------------------------------------------------------------------------
__global__ __launch_bounds__(256) void k6_out(
    const float* __restrict__ xc, const float* __restrict__ t_buf,
    const float* __restrict__ bn, const float* __restrict__ gamma,
    const float* __restrict__ beta, float* __restrict__ out)
{
    const int idx = blockIdx.x * 256 + threadIdx.x;   // float4 index
    const int o = (idx >> 10) & 63;                    // 1024 float4 per row
    const float invC = 1.0f / (float)(B_ * N_);
    const float mean = bn[o] * invC;
    const float var  = bn[64 + o] * invC - mean * mean;
    const float sc = gamma[o] * rsqrtf(var + 1e-5f);
    const float sh = beta[o] - mean * sc;
    const float4 t4 = ((const float4*)t_buf)[idx];
    const float4 c4 = ((const float4*)xc)[idx];
    float4 r;
    r.x = c4.x + fmaxf(0.f, sc * t4.x + sh);
    r.y = c4.y + fmaxf(0.f, sc * t4.y + sh);
    r.z = c4.z + fmaxf(0.f, sc * t4.z + sh);
    r.w = c4.w + fmaxf(0.f, sc * t4.w + sh);
    ((float4*)out)[idx] = r;
}

extern "C" void kernel_launch(void* const* d_in, const int* in_sizes, int n_in,
                              void* d_out, int out_size, void* d_ws, size_t ws_size,
                              hipStream_t stream) {
    const float* x     = (const float*)d_in[0];
    const float* w_qk  = (const float*)d_in[1];
    const float* w_v   = (const float*)d_in[2];
    const float* b_v   = (const float*)d_in[3];
    const float* w_x   = (const float*)d_in[4];
    const float* w_t   = (const float*)d_in[5];
    const float* b_t   = (const float*)d_in[6];
    const float* gamma = (const float*)d_in[7];
    const float* beta  = (const float*)d_in[8];
    float* out = (float*)d_out;

    char* ws = (char*)d_ws;
    unsigned short* qk_t  = (unsigned short*)ws;                 // 4 MB
    unsigned short* xv_bf = (unsigned short*)(ws + (4  << 20));  // 4 MB
    float* xc     = (float*)(ws + (8  << 20));                   // 8 MB
    float* xr     = (float*)(ws + (16 << 20));                   // 8 MB
    float* tbuf   = (float*)(ws + (24 << 20));                   // 8 MB
    float* rowoff = (float*)(ws + (32 << 20));                   // 128 KB
    float* bn     = (float*)(ws + (32 << 20) + (1 << 19));       // 512 B

    hipLaunchKernelGGL(k1_proj,     dim3(16, 8, 16), 256, 0, stream,
                       x, w_qk, w_v, b_v, w_x, qk_t, xv_bf, xc);
    hipLaunchKernelGGL(k2_rowstats, dim3(512),       256, 0, stream, qk_t, rowoff);
    hipLaunchKernelGGL(k3_pv,       dim3(512),       256, 0, stream, qk_t, xv_bf, rowoff, xr);
    hipLaunchKernelGGL(k4_t,        dim3(64, 8),     256, 0, stream, xc, xr, w_t, b_t, tbuf);
    hipLaunchKernelGGL(k5_bnstats,  dim3(64),        256, 0, stream, tbuf, bn);
    hipLaunchKernelGGL(k6_out,      dim3(2048),      256, 0, stream, xc, tbuf, bn, gamma, beta, out);
}

// Round 3
// 281.453 us; speedup vs baseline: 1.8399x; 1.8374x over previous
//
#include <hip/hip_runtime.h>

#define B_   8
#define C_   128
#define N_   4096
#define C2_  64

typedef __bf16 bf16x8 __attribute__((ext_vector_type(8)));
typedef float  f32x4  __attribute__((ext_vector_type(4)));

#define MFMA16(a, b, c) __builtin_amdgcn_mfma_f32_16x16x32_bf16((a), (b), (c), 0, 0, 0)

// sqrt(log2(e)): fold into q/k so softmax uses exp2 directly (E' = E * log2e)
#define QK_SCALE 1.2011224087864498f

static __device__ __forceinline__ unsigned short f2bf(float f) {
    union { __bf16 b; unsigned short u; } cv;
    cv.b = (__bf16)f;
    return cv.u;
}

struct us4 { unsigned short a, b, c, d; };

// async global->LDS, 16 B per lane.  LDS dest must be linear in lane order.
static __device__ __forceinline__ void gl_lds16(const unsigned short* g, void* l) {
    __builtin_amdgcn_global_load_lds(
        (const __attribute__((address_space(1))) unsigned int*)g,
        (__attribute__((address_space(3))) unsigned int*)l,
        16, 0, 0);
}

// ---------------------------------------------------------------------------
// K1: projections.  qk_t[b][n][o] (bf16, pre-scaled), xv_bf[b][o][n] (bf16, +b_v),
//     xc[b][o][n] (f32).  Wave handles 1 output channel o x 256 n (float4 x-loads).
// ---------------------------------------------------------------------------
__global__ __launch_bounds__(256) void k1_proj(
    const float* __restrict__ x, const float* __restrict__ w_qk,
    const float* __restrict__ w_v, const float* __restrict__ b_v,
    const float* __restrict__ w_x,
    unsigned short* __restrict__ qk_t, unsigned short* __restrict__ xv_bf,
    float* __restrict__ xc)
{
    const int wave = threadIdx.x >> 6, lane = threadIdx.x & 63;
    const int b = blockIdx.y;
    const int n_base = blockIdx.x * 256;
    const int o = blockIdx.z * 4 + wave;
    const int n = n_base + lane * 4;

    const float* xb = x + (size_t)b * C_ * N_ + n;
    float aq[4] = {0.f, 0.f, 0.f, 0.f};
    float av[4] = {0.f, 0.f, 0.f, 0.f};
    float ax[4] = {0.f, 0.f, 0.f, 0.f};

    for (int c = 0; c < C_; ++c) {
        const float4 xv4 = *(const float4*)(xb + (size_t)c * N_);
        const float wq = w_qk[o * C_ + c];
        const float wv = w_v[o * C_ + c];
        const float wx = w_x[o * C_ + c];
        aq[0] += wq * xv4.x; aq[1] += wq * xv4.y; aq[2] += wq * xv4.z; aq[3] += wq * xv4.w;
        av[0] += wv * xv4.x; av[1] += wv * xv4.y; av[2] += wv * xv4.z; av[3] += wv * xv4.w;
        ax[0] += wx * xv4.x; ax[1] += wx * xv4.y; ax[2] += wx * xv4.z; ax[3] += wx * xv4.w;
    }
    const float bv = b_v[o];

    #pragma unroll
    for (int j = 0; j < 4; ++j)
        qk_t[(size_t)(b * N_ + n + j) * C2_ + o] = f2bf(aq[j] * QK_SCALE);

    us4 sv;
    sv.a = f2bf(av[0] + bv); sv.b = f2bf(av[1] + bv);
    sv.c = f2bf(av[2] + bv); sv.d = f2bf(av[3] + bv);
    *(us4*)(xv_bf + (size_t)(b * C2_ + o) * N_ + n) = sv;

    float4 cv4;
    cv4.x = ax[0]; cv4.y = ax[1]; cv4.z = ax[2]; cv4.w = ax[3];
    *(float4*)(xc + (size_t)(b * C2_ + o) * N_ + n) = cv4;
}

// ---------------------------------------------------------------------------
// K2: rowoff[b][n] = log2(sum_m 2^E[n][m]).  No max shift needed (|E'|<~60).
//     qk m-slab staged to LDS via global_load_lds (dbuf, XOR-swizzled segs);
//     waves read B-frags with ds_read_b128.  Grid 512 (b = id&7), 2 blocks/CU.
// ---------------------------------------------------------------------------
__global__ __launch_bounds__(256) void k2_rowstats(
    const unsigned short* __restrict__ qk_t, float* __restrict__ rowoff)
{
    __shared__ __align__(16) unsigned char lds_raw[2 * 8192];
    const int tid = threadIdx.x;
    const int wave = tid >> 6, lane = tid & 63;
    const int quad = lane >> 4, col = lane & 15;
    const int b = blockIdx.x & 7;
    const int n_base = (blockIdx.x >> 3) * 64 + wave * 16;
    const unsigned short* qb = qk_t + (size_t)b * N_ * C2_;

    // persistent A-fragments: this wave's 16 n-rows (one-time scattered load)
    const bf16x8 a0 = *(const bf16x8*)(qb + (size_t)(n_base + col) * C2_ + quad * 8);
    const bf16x8 a1 = *(const bf16x8*)(qb + (size_t)(n_base + col) * C2_ + quad * 8 + 32);

    // stage m-slab [m0..m0+64) rows x 128B into buffer p (seg XOR swizzle)
    auto stage = [&](int m0, int p) {
        unsigned char* base = lds_raw + p * 8192;
        #pragma unroll
        for (int r = 0; r < 2; ++r) {
            const int idx = r * 256 + tid;
            const int row = idx >> 3, seg = idx & 7;
            gl_lds16(qb + (size_t)(m0 + row) * C2_ + (size_t)(seg ^ (row & 7)) * 8,
                     base + idx * 16);
        }
    };

    float run_s[4] = {0.f, 0.f, 0.f, 0.f};
    stage(0, 0);
    __syncthreads();

    for (int c = 0; c < 64; ++c) {
        const int p = c & 1;
        if (c + 1 < 64) stage((c + 1) * 64, 1 - p);
        const unsigned short* qt = (const unsigned short*)(lds_raw + p * 8192);
        #pragma unroll
        for (int ms = 0; ms < 4; ++ms) {
            const int row = ms * 16 + col;
            const bf16x8 b0 = *(const bf16x8*)(qt + row * 64 + ((quad ^ (col & 7)) * 8));
            const bf16x8 b1 = *(const bf16x8*)(qt + row * 64 + (((4 + quad) ^ (col & 7)) * 8));
            f32x4 acc = {0.f, 0.f, 0.f, 0.f};
            acc = MFMA16(a0, b0, acc);
            acc = MFMA16(a1, b1, acc);
            #pragma unroll
            for (int r = 0; r < 4; ++r)
                run_s[r] += __builtin_amdgcn_exp2f(acc[r]);
        }
        __syncthreads();
    }

    #pragma unroll
    for (int r = 0; r < 4; ++r) {
        #pragma unroll
        for (int off = 1; off < 16; off <<= 1)
            run_s[r] += __shfl_xor(run_s[r], off, 64);
    }
    if (col == 0) {
        #pragma unroll
        for (int r = 0; r < 4; ++r)
            rowoff[b * N_ + n_base + quad * 4 + r] = __builtin_amdgcn_logf(run_s[r]);
    }
}

// ---------------------------------------------------------------------------
// K3: block owns 128 m-cols (4 waves x 32).  Per 64-n chunk: stage qk slab +
//     xv tile to LDS (global_load_lds dbuf); E = MFMA from LDS frags;
//     S = exp2(E-off) -> LDS round-trip (C-layout -> B-operand); PV MFMA;
//     colsum; x_r = Y/(1e-9+colsum).  Grid 256 (b = id&7).
// ---------------------------------------------------------------------------
__global__ __launch_bounds__(256) void k3_pv(
    const unsigned short* __restrict__ qk_t, const unsigned short* __restrict__ xv_bf,
    const float* __restrict__ rowoff, float* __restrict__ xr)
{
    // 0..16K: qk dbuf | 16K..32K: xv dbuf | 32K..50K: S tiles (4 waves x 2 x 16x72)
    __shared__ __align__(16) unsigned char lds_raw[32768 + 8 * 2304];
    const int tid = threadIdx.x;
    const int wave = tid >> 6, lane = tid & 63;
    const int quad = lane >> 4, col = lane & 15;
    const int b = blockIdx.x & 7;
    const int m_blk = (blockIdx.x >> 3) * 128;
    const int m_wave = m_blk + wave * 32;
    const unsigned short* qb = qk_t + (size_t)b * N_ * C2_;
    const unsigned short* vb = xv_bf + (size_t)b * C2_ * N_;
    const float* ro = rowoff + b * N_;

    // persistent B-operands for E: this wave's 32 m-cols (2 groups of 16)
    bf16x8 kb0[2], kb1[2];
    #pragma unroll
    for (int g = 0; g < 2; ++g) {
        const unsigned short* p = qb + (size_t)(m_wave + g * 16 + col) * C2_ + quad * 8;
        kb0[g] = *(const bf16x8*)p;
        kb1[g] = *(const bf16x8*)(p + 32);
    }

    unsigned short (*st_s[2])[72];
    st_s[0] = (unsigned short(*)[72])(lds_raw + 32768 + (wave * 2 + 0) * 2304);
    st_s[1] = (unsigned short(*)[72])(lds_raw + 32768 + (wave * 2 + 1) * 2304);

    auto stage = [&](int n0, int p) {
        unsigned char* qbase = lds_raw + p * 8192;
        unsigned char* vbase = lds_raw + 16384 + p * 8192;
        #pragma unroll
        for (int r = 0; r < 2; ++r) {
            const int idx = r * 256 + tid;
            const int row = idx >> 3, seg = idx & 7;
            const int ss = seg ^ (row & 7);
            gl_lds16(qb + (size_t)(n0 + row) * C2_ + (size_t)ss * 8, qbase + idx * 16);
            gl_lds16(vb + (size_t)row * N_ + n0 + ss * 8, vbase + idx * 16);
        }
    };

    f32x4 accY[2][4];
    #pragma unroll
    for (int g = 0; g < 2; ++g)
        #pragma unroll
        for (int os = 0; os < 4; ++os) accY[g][os] = (f32x4){0.f, 0.f, 0.f, 0.f};
    float colacc[2] = {0.f, 0.f};

    stage(0, 0);
    __syncthreads();

    for (int c = 0; c < 64; ++c) {
        const int n0 = c * 64;
        const int p = c & 1;
        if (c + 1 < 64) stage(n0 + 64, 1 - p);

        float4 ro4[4];
        #pragma unroll
        for (int ns = 0; ns < 4; ++ns)
            ro4[ns] = *(const float4*)(ro + n0 + ns * 16 + quad * 4);

        const unsigned short* qt = (const unsigned short*)(lds_raw + p * 8192);
        const unsigned short* vt = (const unsigned short*)(lds_raw + 16384 + p * 8192);

        // E phase: S tiles written to LDS in C-layout
        #pragma unroll
        for (int ns = 0; ns < 4; ++ns) {
            const int row = ns * 16 + col;
            const bf16x8 qa0 = *(const bf16x8*)(qt + row * 64 + ((quad ^ (col & 7)) * 8));
            const bf16x8 qa1 = *(const bf16x8*)(qt + row * 64 + (((4 + quad) ^ (col & 7)) * 8));
            const float* rr = (const float*)&ro4[ns];
            #pragma unroll
            for (int g = 0; g < 2; ++g) {
                f32x4 acc = {0.f, 0.f, 0.f, 0.f};
                acc = MFMA16(qa0, kb0[g], acc);
                acc = MFMA16(qa1, kb1[g], acc);
                union { unsigned short us[4]; uint2 u2; } pk;
                #pragma unroll
                for (int r = 0; r < 4; ++r) {
                    const float s = __builtin_amdgcn_exp2f(acc[r] - rr[r]);
                    colacc[g] += s;
                    pk.us[r] = f2bf(s);
                }
                *(uint2*)&st_s[g][col][ns * 16 + quad * 4] = pk.u2;
            }
        }

        // PV phase: S as B-operand (same-wave LDS round-trip), xv frags from LDS
        bf16x8 sB0[2], sB1[2];
        #pragma unroll
        for (int g = 0; g < 2; ++g) {
            sB0[g] = *(const bf16x8*)&st_s[g][col][quad * 8];
            sB1[g] = *(const bf16x8*)&st_s[g][col][32 + quad * 8];
        }
        #pragma unroll
        for (int os = 0; os < 4; ++os) {
            const int o = os * 16 + col;
            const bf16x8 va0 = *(const bf16x8*)(vt + o * 64 + ((quad ^ (col & 7)) * 8));
            const bf16x8 va1 = *(const bf16x8*)(vt + o * 64 + (((4 + quad) ^ (col & 7)) * 8));
            #pragma unroll
            for (int g = 0; g < 2; ++g) {
                accY[g][os] = MFMA16(va0, sB0[g], accY[g][os]);
                accY[g][os] = MFMA16(va1, sB1[g], accY[g][os]);
            }
        }
        __syncthreads();
    }

    #pragma unroll
    for (int g = 0; g < 2; ++g) {
        colacc[g] += __shfl_xor(colacc[g], 16, 64);
        colacc[g] += __shfl_xor(colacc[g], 32, 64);
        const float inv = 1.f / (1e-9f + colacc[g]);
        #pragma unroll
        for (int os = 0; os < 4; ++os)
            #pragma unroll
            for (int r = 0; r < 4; ++r)
                xr[(size_t)(b * C2_ + os * 16 + quad * 4 + r) * N_ + m_wave + g * 16 + col]
                    = accY[g][os][r] * inv;
    }
}

// ---------------------------------------------------------------------------
// K4: t = w_t @ (xc - xr) + b_t, per (b, 64-n tile).  d-tile + w_t in LDS.
// ---------------------------------------------------------------------------
__global__ __launch_bounds__(256) void k4_t(
    const float* __restrict__ xc, const float* __restrict__ xr,
    const float* __restrict__ w_t, const float* __restrict__ b_t,
    float* __restrict__ t_buf)
{
    __shared__ float d_lds[64][64];
    __shared__ float w_lds[64][64];
    const int b = blockIdx.y;
    const int n0 = blockIdx.x * 64;
    const size_t base = (size_t)b * C2_ * N_;

    for (int idx = threadIdx.x; idx < 4096; idx += 256) {
        const int i = idx >> 6, n = idx & 63;
        const size_t g = base + (size_t)i * N_ + n0 + n;
        d_lds[i][n] = xc[g] - xr[g];
        w_lds[i][n] = w_t[idx];
    }
    __syncthreads();

    const int n = threadIdx.x & 63, ow = (threadIdx.x >> 6) * 16;
    float acc[16];
    #pragma unroll
    for (int oo = 0; oo < 16; ++oo) acc[oo] = 0.f;
    for (int i = 0; i < 64; ++i) {
        const float dv = d_lds[i][n];
        #pragma unroll
        for (int oo = 0; oo < 16; ++oo)
            acc[oo] += w_lds[ow + oo][i] * dv;
    }
    #pragma unroll
    for (int oo = 0; oo < 16; ++oo)
        t_buf[base + (size_t)(ow + oo) * N_ + n0 + n] = acc[oo] + b_t[ow + oo];
}

// ---------------------------------------------------------------------------
// K5: BN batch stats per channel (sum, sumsq over B*N).  One block per o.
// ---------------------------------------------------------------------------
__global__ __launch_bounds__(256) void k5_bnstats(
    const float* __restrict__ t_buf, float* __restrict__ bn)
{
    const int o = blockIdx.x;
    float s = 0.f, s2 = 0.f;
    for (int b = 0; b < B_; ++b) {
        const float4* p = (const float4*)(t_buf + (size_t)(b * C2_ + o) * N_);
        for (int j = threadIdx.x; j < N_ / 4; j += 256) {
            const float4 v = p[j];
            s  += v.x + v.y + v.z + v.w;
            s2 += v.x * v.x + v.y * v.y + v.z * v.z + v.w * v.w;
        }
    }
    #pragma unroll
    for (int off = 1; off < 64; off <<= 1) {
        s  += __shfl_xor(s, off, 64);
        s2 += __shfl_xor(s2, off, 64);
    }
    __shared__ float red[2][4];
    if ((threadIdx.x & 63) == 0) {
        red[0][threadIdx.x >> 6] = s;
        red[1][threadIdx.x >> 6] = s2;
    }
    __syncthreads();
    if (threadIdx.x == 0) {
        bn[o]       = red[0][0] + red[0][1] + red[0][2] + red[0][3];
        bn[64 + o]  = red[1][0] + red[1][1] + red[1][2] + red[1][3];
    }
}

// ---------------------------------------------------------------------------
// K6: out = xc + relu(gamma * (t - mean) * rsqrt(var + eps) + beta)
// ---------------------------------------------------------------------------
__global__ __launch_bounds__(256) void k6_out(
    const float* __restrict__ xc, const float* __restrict__ t_buf,
    const float* __restrict__ bn, const float* __restrict__ gamma,
    const float* __restrict__ beta, float* __restrict__ out)
{
    const int idx = blockIdx.x * 256 + threadIdx.x;
    const int o = (idx >> 10) & 63;
    const float invC = 1.0f / (float)(B_ * N_);
    const float mean = bn[o] * invC;
    const float var  = bn[64 + o] * invC - mean * mean;
    const float sc = gamma[o] * rsqrtf(var + 1e-5f);
    const float sh = beta[o] - mean * sc;
    const float4 t4 = ((const float4*)t_buf)[idx];
    const float4 c4 = ((const float4*)xc)[idx];
    float4 r;
    r.x = c4.x + fmaxf(0.f, sc * t4.x + sh);
    r.y = c4.y + fmaxf(0.f, sc * t4.y + sh);
    r.z = c4.z + fmaxf(0.f, sc * t4.z + sh);
    r.w = c4.w + fmaxf(0.f, sc * t4.w + sh);
    ((float4*)out)[idx] = r;
}

extern "C" void kernel_launch(void* const* d_in, const int* in_sizes, int n_in,
                              void* d_out, int out_size, void* d_ws, size_t ws_size,
                              hipStream_t stream) {
    const float* x     = (const float*)d_in[0];
    const float* w_qk  = (const float*)d_in[1];
    const float* w_v   = (const float*)d_in[2];
    const float* b_v   = (const float*)d_in[3];
    const float* w_x   = (const float*)d_in[4];
    const float* w_t   = (const float*)d_in[5];
    const float* b_t   = (const float*)d_in[6];
    const float* gamma = (const float*)d_in[7];
    const float* beta  = (const float*)d_in[8];
    float* out = (float*)d_out;

    char* ws = (char*)d_ws;
    unsigned short* qk_t  = (unsigned short*)ws;
    unsigned short* xv_bf = (unsigned short*)(ws + (4  << 20));
    float* xc     = (float*)(ws + (8  << 20));
    float* xr     = (float*)(ws + (16 << 20));
    float* tbuf   = (float*)(ws + (24 << 20));
    float* rowoff = (float*)(ws + (32 << 20));
    float* bn     = (float*)(ws + (32 << 20) + (1 << 19));

    hipLaunchKernelGGL(k1_proj,     dim3(16, 8, 16), 256, 0, stream,
                       x, w_qk, w_v, b_v, w_x, qk_t, xv_bf, xc);
    hipLaunchKernelGGL(k2_rowstats, dim3(512),       256, 0, stream, qk_t, rowoff);
    hipLaunchKernelGGL(k3_pv,       dim3(256),       256, 0, stream, qk_t, xv_bf, rowoff, xr);
    hipLaunchKernelGGL(k4_t,        dim3(64, 8),     256, 0, stream, xc, xr, w_t, b_t, tbuf);
    hipLaunchKernelGGL(k5_bnstats,  dim3(64),        256, 0, stream, tbuf, bn);
    hipLaunchKernelGGL(k6_out,      dim3(2048),      256, 0, stream, xc, tbuf, bn, gamma, beta, out);
}

// Round 4
// 247.593 us; speedup vs baseline: 2.0915x; 1.1368x over previous
//
#include <hip/hip_runtime.h>

#define B_   8
#define C_   128
#define N_   4096
#define C2_  64

typedef __bf16 bf16x8 __attribute__((ext_vector_type(8)));
typedef float  f32x4  __attribute__((ext_vector_type(4)));

#define MFMA16(a, b, c) __builtin_amdgcn_mfma_f32_16x16x32_bf16((a), (b), (c), 0, 0, 0)

// sqrt(log2(e)): fold into q/k so softmax uses exp2 directly (E' = E * log2e)
#define QK_SCALE 1.2011224087864498f

static __device__ __forceinline__ unsigned short f2bf(float f) {
    union { __bf16 b; unsigned short u; } cv;
    cv.b = (__bf16)f;
    return cv.u;
}

struct us4 { unsigned short a, b, c, d; };

// async global->LDS, 16 B per lane.  LDS dest must be linear in lane order.
static __device__ __forceinline__ void gl_lds16(const unsigned short* g, void* l) {
    __builtin_amdgcn_global_load_lds(
        (const __attribute__((address_space(1))) unsigned int*)g,
        (__attribute__((address_space(3))) unsigned int*)l,
        16, 0, 0);
}

// ---------------------------------------------------------------------------
// K1: projections.  qk_t[b][n][o] (bf16, pre-scaled), xv_bf[b][o][n] (bf16, +b_v),
//     xc[b][o][n] (f32).  Wave handles 1 output channel o x 256 n (float4 x-loads).
// ---------------------------------------------------------------------------
__global__ __launch_bounds__(256) void k1_proj(
    const float* __restrict__ x, const float* __restrict__ w_qk,
    const float* __restrict__ w_v, const float* __restrict__ b_v,
    const float* __restrict__ w_x,
    unsigned short* __restrict__ qk_t, unsigned short* __restrict__ xv_bf,
    float* __restrict__ xc)
{
    const int wave = threadIdx.x >> 6, lane = threadIdx.x & 63;
    const int b = blockIdx.y;
    const int n_base = blockIdx.x * 256;
    const int o = blockIdx.z * 4 + wave;
    const int n = n_base + lane * 4;

    const float* xb = x + (size_t)b * C_ * N_ + n;
    float aq[4] = {0.f, 0.f, 0.f, 0.f};
    float av[4] = {0.f, 0.f, 0.f, 0.f};
    float ax[4] = {0.f, 0.f, 0.f, 0.f};

    for (int c = 0; c < C_; ++c) {
        const float4 xv4 = *(const float4*)(xb + (size_t)c * N_);
        const float wq = w_qk[o * C_ + c];
        const float wv = w_v[o * C_ + c];
        const float wx = w_x[o * C_ + c];
        aq[0] += wq * xv4.x; aq[1] += wq * xv4.y; aq[2] += wq * xv4.z; aq[3] += wq * xv4.w;
        av[0] += wv * xv4.x; av[1] += wv * xv4.y; av[2] += wv * xv4.z; av[3] += wv * xv4.w;
        ax[0] += wx * xv4.x; ax[1] += wx * xv4.y; ax[2] += wx * xv4.z; ax[3] += wx * xv4.w;
    }
    const float bv = b_v[o];

    #pragma unroll
    for (int j = 0; j < 4; ++j)
        qk_t[(size_t)(b * N_ + n + j) * C2_ + o] = f2bf(aq[j] * QK_SCALE);

    us4 sv;
    sv.a = f2bf(av[0] + bv); sv.b = f2bf(av[1] + bv);
    sv.c = f2bf(av[2] + bv); sv.d = f2bf(av[3] + bv);
    *(us4*)(xv_bf + (size_t)(b * C2_ + o) * N_ + n) = sv;

    float4 cv4;
    cv4.x = ax[0]; cv4.y = ax[1]; cv4.z = ax[2]; cv4.w = ax[3];
    *(float4*)(xc + (size_t)(b * C2_ + o) * N_ + n) = cv4;
}

// ---------------------------------------------------------------------------
// K2: partial row softmax sums.  Grid 2048: b=id&7, nblk=(id>>3)&63, mq=id>>9.
//     Each block scans m in [mq*1024, +1024) (16 chunks of 64), accumulating
//     per-lane sum_m 2^E; writes part_rs[mq][b][n].  8 blocks/CU.
// ---------------------------------------------------------------------------
__global__ __launch_bounds__(256) void k2_rowstats(
    const unsigned short* __restrict__ qk_t, float* __restrict__ part_rs)
{
    __shared__ __align__(16) unsigned char lds_raw[2 * 8192];
    const int tid = threadIdx.x;
    const int wave = tid >> 6, lane = tid & 63;
    const int quad = lane >> 4, col = lane & 15;
    const int b = blockIdx.x & 7;
    const int nblk = (blockIdx.x >> 3) & 63;
    const int mq = blockIdx.x >> 9;
    const int n_base = nblk * 64 + wave * 16;
    const int m_start = mq * 1024;
    const unsigned short* qb = qk_t + (size_t)b * N_ * C2_;

    // persistent A-fragments: this wave's 16 n-rows (one-time scattered load)
    const bf16x8 a0 = *(const bf16x8*)(qb + (size_t)(n_base + col) * C2_ + quad * 8);
    const bf16x8 a1 = *(const bf16x8*)(qb + (size_t)(n_base + col) * C2_ + quad * 8 + 32);

    auto stage = [&](int m0, int p) {
        unsigned char* base = lds_raw + p * 8192;
        #pragma unroll
        for (int r = 0; r < 2; ++r) {
            const int idx = r * 256 + tid;
            const int row = idx >> 3, seg = idx & 7;
            gl_lds16(qb + (size_t)(m0 + row) * C2_ + (size_t)(seg ^ (row & 7)) * 8,
                     base + idx * 16);
        }
    };

    float run_s[4] = {0.f, 0.f, 0.f, 0.f};
    stage(m_start, 0);
    __syncthreads();

    for (int c = 0; c < 16; ++c) {
        const int p = c & 1;
        if (c + 1 < 16) stage(m_start + (c + 1) * 64, 1 - p);
        const unsigned short* qt = (const unsigned short*)(lds_raw + p * 8192);
        #pragma unroll
        for (int ms = 0; ms < 4; ++ms) {
            const int row = ms * 16 + col;
            const bf16x8 b0 = *(const bf16x8*)(qt + row * 64 + ((quad ^ (col & 7)) * 8));
            const bf16x8 b1 = *(const bf16x8*)(qt + row * 64 + (((4 + quad) ^ (col & 7)) * 8));
            f32x4 acc = {0.f, 0.f, 0.f, 0.f};
            acc = MFMA16(a0, b0, acc);
            acc = MFMA16(a1, b1, acc);
            #pragma unroll
            for (int r = 0; r < 4; ++r)
                run_s[r] += __builtin_amdgcn_exp2f(acc[r]);
        }
        __syncthreads();
    }

    #pragma unroll
    for (int r = 0; r < 4; ++r) {
        #pragma unroll
        for (int off = 1; off < 16; off <<= 1)
            run_s[r] += __shfl_xor(run_s[r], off, 64);
    }
    if (col == 0) {
        #pragma unroll
        for (int r = 0; r < 4; ++r)
            part_rs[((size_t)(mq * 8 + b) << 12) + n_base + quad * 4 + r] = run_s[r];
    }
}

// K2b: rowoff[b][n] = log2(sum_q part_rs[q][b][n])
__global__ __launch_bounds__(256) void k2b_comb(
    const float* __restrict__ part_rs, float* __restrict__ rowoff)
{
    const int i = blockIdx.x * 256 + threadIdx.x;   // [0, 32768)
    const int b = i >> 12, n = i & 4095;
    float s = 0.f;
    #pragma unroll
    for (int q = 0; q < 4; ++q)
        s += part_rs[((size_t)(q * 8 + b) << 12) + n];
    rowoff[i] = __builtin_amdgcn_logf(s);
}

// ---------------------------------------------------------------------------
// K3: block owns 128 m-cols (4 waves x 32) and HALF the n-range (split-K).
//     Grid 512: b=id&7, mblk=(id>>3)&31, nh=id>>8.  Per 64-n chunk: stage qk
//     slab + xv tile (global_load_lds dbuf); E = MFMA; S = exp2(E-off) via
//     LDS round-trip; PV MFMA; partial colsum.  Writes partial Y (f32) and
//     partial colsum; k3b combines.  2 blocks/CU overlap barrier stalls.
// ---------------------------------------------------------------------------
__global__ __launch_bounds__(256) void k3_pv(
    const unsigned short* __restrict__ qk_t, const unsigned short* __restrict__ xv_bf,
    const float* __restrict__ rowoff, float* __restrict__ yp0, float* __restrict__ yp1,
    float* __restrict__ cspart)
{
    // 0..16K: qk dbuf | 16K..32K: xv dbuf | 32K..50K: S tiles (4 waves x 2 x 16x72)
    __shared__ __align__(16) unsigned char lds_raw[32768 + 8 * 2304];
    const int tid = threadIdx.x;
    const int wave = tid >> 6, lane = tid & 63;
    const int quad = lane >> 4, col = lane & 15;
    const int b = blockIdx.x & 7;
    const int m_blk = ((blockIdx.x >> 3) & 31) * 128;
    const int nh = blockIdx.x >> 8;                  // 0 or 1
    const int n_start = nh * 2048;
    const int m_wave = m_blk + wave * 32;
    const unsigned short* qb = qk_t + (size_t)b * N_ * C2_;
    const unsigned short* vb = xv_bf + (size_t)b * C2_ * N_;
    const float* ro = rowoff + b * N_;
    float* yp = nh ? yp1 : yp0;

    // persistent B-operands for E: this wave's 32 m-cols (2 groups of 16)
    bf16x8 kb0[2], kb1[2];
    #pragma unroll
    for (int g = 0; g < 2; ++g) {
        const unsigned short* p = qb + (size_t)(m_wave + g * 16 + col) * C2_ + quad * 8;
        kb0[g] = *(const bf16x8*)p;
        kb1[g] = *(const bf16x8*)(p + 32);
    }

    unsigned short (*st_s[2])[72];
    st_s[0] = (unsigned short(*)[72])(lds_raw + 32768 + (wave * 2 + 0) * 2304);
    st_s[1] = (unsigned short(*)[72])(lds_raw + 32768 + (wave * 2 + 1) * 2304);

    auto stage = [&](int n0, int p) {
        unsigned char* qbase = lds_raw + p * 8192;
        unsigned char* vbase = lds_raw + 16384 + p * 8192;
        #pragma unroll
        for (int r = 0; r < 2; ++r) {
            const int idx = r * 256 + tid;
            const int row = idx >> 3, seg = idx & 7;
            const int ss = seg ^ (row & 7);
            gl_lds16(qb + (size_t)(n0 + row) * C2_ + (size_t)ss * 8, qbase + idx * 16);
            gl_lds16(vb + (size_t)row * N_ + n0 + ss * 8, vbase + idx * 16);
        }
    };

    f32x4 accY[2][4];
    #pragma unroll
    for (int g = 0; g < 2; ++g)
        #pragma unroll
        for (int os = 0; os < 4; ++os) accY[g][os] = (f32x4){0.f, 0.f, 0.f, 0.f};
    float colacc[2] = {0.f, 0.f};

    stage(n_start, 0);
    __syncthreads();

    for (int c = 0; c < 32; ++c) {
        const int n0 = n_start + c * 64;
        const int p = c & 1;
        if (c + 1 < 32) stage(n0 + 64, 1 - p);

        float4 ro4[4];
        #pragma unroll
        for (int ns = 0; ns < 4; ++ns)
            ro4[ns] = *(const float4*)(ro + n0 + ns * 16 + quad * 4);

        const unsigned short* qt = (const unsigned short*)(lds_raw + p * 8192);
        const unsigned short* vt = (const unsigned short*)(lds_raw + 16384 + p * 8192);

        // E phase: S tiles written to LDS in C-layout
        #pragma unroll
        for (int ns = 0; ns < 4; ++ns) {
            const int row = ns * 16 + col;
            const bf16x8 qa0 = *(const bf16x8*)(qt + row * 64 + ((quad ^ (col & 7)) * 8));
            const bf16x8 qa1 = *(const bf16x8*)(qt + row * 64 + (((4 + quad) ^ (col & 7)) * 8));
            const float* rr = (const float*)&ro4[ns];
            #pragma unroll
            for (int g = 0; g < 2; ++g) {
                f32x4 acc = {0.f, 0.f, 0.f, 0.f};
                acc = MFMA16(qa0, kb0[g], acc);
                acc = MFMA16(qa1, kb1[g], acc);
                union { unsigned short us[4]; uint2 u2; } pk;
                #pragma unroll
                for (int r = 0; r < 4; ++r) {
                    const float s = __builtin_amdgcn_exp2f(acc[r] - rr[r]);
                    colacc[g] += s;
                    pk.us[r] = f2bf(s);
                }
                *(uint2*)&st_s[g][col][ns * 16 + quad * 4] = pk.u2;
            }
        }

        // PV phase: S as B-operand (same-wave LDS round-trip), xv frags from LDS
        bf16x8 sB0[2], sB1[2];
        #pragma unroll
        for (int g = 0; g < 2; ++g) {
            sB0[g] = *(const bf16x8*)&st_s[g][col][quad * 8];
            sB1[g] = *(const bf16x8*)&st_s[g][col][32 + quad * 8];
        }
        #pragma unroll
        for (int os = 0; os < 4; ++os) {
            const int o = os * 16 + col;
            const bf16x8 va0 = *(const bf16x8*)(vt + o * 64 + ((quad ^ (col & 7)) * 8));
            const bf16x8 va1 = *(const bf16x8*)(vt + o * 64 + (((4 + quad) ^ (col & 7)) * 8));
            #pragma unroll
            for (int g = 0; g < 2; ++g) {
                accY[g][os] = MFMA16(va0, sB0[g], accY[g][os]);
                accY[g][os] = MFMA16(va1, sB1[g], accY[g][os]);
            }
        }
        __syncthreads();
    }

    #pragma unroll
    for (int g = 0; g < 2; ++g) {
        colacc[g] += __shfl_xor(colacc[g], 16, 64);
        colacc[g] += __shfl_xor(colacc[g], 32, 64);
        if (lane < 16)
            cspart[((size_t)nh * 8 + b) * N_ + m_wave + g * 16 + col] = colacc[g];
        #pragma unroll
        for (int os = 0; os < 4; ++os)
            #pragma unroll
            for (int r = 0; r < 4; ++r)
                yp[(size_t)(b * C2_ + os * 16 + quad * 4 + r) * N_ + m_wave + g * 16 + col]
                    = accY[g][os][r];
    }
}

// K3b: xr = (Y0+Y1) / (1e-9 + cs0+cs1), in-place over the Y0 region.
__global__ __launch_bounds__(256) void k3b_comb(
    float* yp0, const float* __restrict__ yp1,
    const float* __restrict__ cspart)
{
    const int idx4 = blockIdx.x * 256 + threadIdx.x;  // [0, 524288) float4 idx
    const int b = idx4 >> 16;
    const int m4 = idx4 & 1023;
    const float4 y0 = ((const float4*)yp0)[idx4];
    const float4 y1 = ((const float4*)yp1)[idx4];
    const float4 c0 = ((const float4*)cspart)[b * 1024 + m4];
    const float4 c1 = ((const float4*)cspart)[8192 + b * 1024 + m4];
    float4 r;
    r.x = (y0.x + y1.x) / (1e-9f + c0.x + c1.x);
    r.y = (y0.y + y1.y) / (1e-9f + c0.y + c1.y);
    r.z = (y0.z + y1.z) / (1e-9f + c0.z + c1.z);
    r.w = (y0.w + y1.w) / (1e-9f + c0.w + c1.w);
    ((float4*)yp0)[idx4] = r;
}

// ---------------------------------------------------------------------------
// K4: t = w_t @ (xc - xr) + b_t, per (b, 64-n tile).  d-tile + w_t in LDS.
// ---------------------------------------------------------------------------
__global__ __launch_bounds__(256) void k4_t(
    const float* __restrict__ xc, const float* __restrict__ xr,
    const float* __restrict__ w_t, const float* __restrict__ b_t,
    float* __restrict__ t_buf)
{
    __shared__ float d_lds[64][64];
    __shared__ float w_lds[64][64];
    const int b = blockIdx.y;
    const int n0 = blockIdx.x * 64;
    const size_t base = (size_t)b * C2_ * N_;

    for (int idx = threadIdx.x; idx < 4096; idx += 256) {
        const int i = idx >> 6, n = idx & 63;
        const size_t g = base + (size_t)i * N_ + n0 + n;
        d_lds[i][n] = xc[g] - xr[g];
        w_lds[i][n] = w_t[idx];
    }
    __syncthreads();

    const int n = threadIdx.x & 63, ow = (threadIdx.x >> 6) * 16;
    float acc[16];
    #pragma unroll
    for (int oo = 0; oo < 16; ++oo) acc[oo] = 0.f;
    for (int i = 0; i < 64; ++i) {
        const float dv = d_lds[i][n];
        #pragma unroll
        for (int oo = 0; oo < 16; ++oo)
            acc[oo] += w_lds[ow + oo][i] * dv;
    }
    #pragma unroll
    for (int oo = 0; oo < 16; ++oo)
        t_buf[base + (size_t)(ow + oo) * N_ + n0 + n] = acc[oo] + b_t[ow + oo];
}

// ---------------------------------------------------------------------------
// K5: BN batch stats per channel (sum, sumsq over B*N).  One block per o.
// ---------------------------------------------------------------------------
__global__ __launch_bounds__(256) void k5_bnstats(
    const float* __restrict__ t_buf, float* __restrict__ bn)
{
    const int o = blockIdx.x;
    float s = 0.f, s2 = 0.f;
    for (int b = 0; b < B_; ++b) {
        const float4* p = (const float4*)(t_buf + (size_t)(b * C2_ + o) * N_);
        for (int j = threadIdx.x; j < N_ / 4; j += 256) {
            const float4 v = p[j];
            s  += v.x + v.y + v.z + v.w;
            s2 += v.x * v.x + v.y * v.y + v.z * v.z + v.w * v.w;
        }
    }
    #pragma unroll
    for (int off = 1; off < 64; off <<= 1) {
        s  += __shfl_xor(s, off, 64);
        s2 += __shfl_xor(s2, off, 64);
    }
    __shared__ float red[2][4];
    if ((threadIdx.x & 63) == 0) {
        red[0][threadIdx.x >> 6] = s;
        red[1][threadIdx.x >> 6] = s2;
    }
    __syncthreads();
    if (threadIdx.x == 0) {
        bn[o]       = red[0][0] + red[0][1] + red[0][2] + red[0][3];
        bn[64 + o]  = red[1][0] + red[1][1] + red[1][2] + red[1][3];
    }
}

// ---------------------------------------------------------------------------
// K6: out = xc + relu(gamma * (t - mean) * rsqrt(var + eps) + beta)
// ---------------------------------------------------------------------------
__global__ __launch_bounds__(256) void k6_out(
    const float* __restrict__ xc, const float* __restrict__ t_buf,
    const float* __restrict__ bn, const float* __restrict__ gamma,
    const float* __restrict__ beta, float* __restrict__ out)
{
    const int idx = blockIdx.x * 256 + threadIdx.x;
    const int o = (idx >> 10) & 63;
    const float invC = 1.0f / (float)(B_ * N_);
    const float mean = bn[o] * invC;
    const float var  = bn[64 + o] * invC - mean * mean;
    const float sc = gamma[o] * rsqrtf(var + 1e-5f);
    const float sh = beta[o] - mean * sc;
    const float4 t4 = ((const float4*)t_buf)[idx];
    const float4 c4 = ((const float4*)xc)[idx];
    float4 r;
    r.x = c4.x + fmaxf(0.f, sc * t4.x + sh);
    r.y = c4.y + fmaxf(0.f, sc * t4.y + sh);
    r.z = c4.z + fmaxf(0.f, sc * t4.z + sh);
    r.w = c4.w + fmaxf(0.f, sc * t4.w + sh);
    ((float4*)out)[idx] = r;
}

extern "C" void kernel_launch(void* const* d_in, const int* in_sizes, int n_in,
                              void* d_out, int out_size, void* d_ws, size_t ws_size,
                              hipStream_t stream) {
    const float* x     = (const float*)d_in[0];
    const float* w_qk  = (const float*)d_in[1];
    const float* w_v   = (const float*)d_in[2];
    const float* b_v   = (const float*)d_in[3];
    const float* w_x   = (const float*)d_in[4];
    const float* w_t   = (const float*)d_in[5];
    const float* b_t   = (const float*)d_in[6];
    const float* gamma = (const float*)d_in[7];
    const float* beta  = (const float*)d_in[8];
    float* out = (float*)d_out;

    char* ws = (char*)d_ws;
    unsigned short* qk_t  = (unsigned short*)ws;                      // 4 MB
    unsigned short* xv_bf = (unsigned short*)(ws + (4  << 20));       // 4 MB
    float* xc      = (float*)(ws + (8  << 20));                       // 8 MB
    float* xr_yp0  = (float*)(ws + (16 << 20));                       // 8 MB (ypart0 -> xr in place)
    float* tb_yp1  = (float*)(ws + (24 << 20));                       // 8 MB (ypart1, then t_buf)
    float* part_rs = (float*)(ws + (32 << 20));                       // 512 KB
    float* rowoff  = (float*)(ws + (32 << 20) + (512 << 10));         // 128 KB
    float* cspart  = (float*)(ws + (32 << 20) + (640 << 10));         // 256 KB
    float* bn      = (float*)(ws + (32 << 20) + (896 << 10));         // 512 B

    hipLaunchKernelGGL(k1_proj,     dim3(16, 8, 16), 256, 0, stream,
                       x, w_qk, w_v, b_v, w_x, qk_t, xv_bf, xc);
    hipLaunchKernelGGL(k2_rowstats, dim3(2048),      256, 0, stream, qk_t, part_rs);
    hipLaunchKernelGGL(k2b_comb,    dim3(128),       256, 0, stream, part_rs, rowoff);
    hipLaunchKernelGGL(k3_pv,       dim3(512),       256, 0, stream,
                       qk_t, xv_bf, rowoff, xr_yp0, tb_yp1, cspart);
    hipLaunchKernelGGL(k3b_comb,    dim3(2048),      256, 0, stream, xr_yp0, tb_yp1, cspart);
    hipLaunchKernelGGL(k4_t,        dim3(64, 8),     256, 0, stream, xc, xr_yp0, w_t, b_t, tb_yp1);
    hipLaunchKernelGGL(k5_bnstats,  dim3(64),        256, 0, stream, tb_yp1, bn);
    hipLaunchKernelGGL(k6_out,      dim3(2048),      256, 0, stream, xc, tb_yp1, bn, gamma, beta, out);
}

// Round 5
// 201.441 us; speedup vs baseline: 2.5707x; 1.2291x over previous
//
#include <hip/hip_runtime.h>

#define B_   8
#define C_   128
#define N_   4096
#define C2_  64

typedef __bf16 bf16x8 __attribute__((ext_vector_type(8)));
typedef float  f32x4  __attribute__((ext_vector_type(4)));

#define MFMA16(a, b, c) __builtin_amdgcn_mfma_f32_16x16x32_bf16((a), (b), (c), 0, 0, 0)

// sqrt(log2(e)): fold into q/k so softmax uses exp2 directly (E' = E * log2e)
#define QK_SCALE 1.2011224087864498f

static __device__ __forceinline__ unsigned short f2bf(float f) {
    union { __bf16 b; unsigned short u; } cv;
    cv.b = (__bf16)f;
    return cv.u;
}

struct us4 { unsigned short a, b, c, d; };

// async global->LDS, 16 B per lane.  LDS dest must be linear in lane order.
static __device__ __forceinline__ void gl_lds16(const unsigned short* g, void* l) {
    __builtin_amdgcn_global_load_lds(
        (const __attribute__((address_space(1))) unsigned int*)g,
        (__attribute__((address_space(3))) unsigned int*)l,
        16, 0, 0);
}

// ---------------------------------------------------------------------------
// K1: fused projection GEMM.  D[192 o][64 n] = W(3x64 stacked)[o][c] * x[c][n]
//     per (b, 64-n tile).  Weights -> LDS bf16 [192][136]; x tile transposed
//     -> LDS bf16 x_t[64 n][136 c].  A-frag = w rows, B-frag = x_t rows (both
//     16B-contiguous).  Epilogue: ot 0-3 -> qk_t[b][n][o] (us4, *QK_SCALE);
//     ot 4-7 -> xv_bf[b][o][n] (+b_v); ot 8-11 -> xc[b][o][n] (f32).
// ---------------------------------------------------------------------------
__global__ __launch_bounds__(256) void k1_proj(
    const float* __restrict__ x, const float* __restrict__ w_qk,
    const float* __restrict__ w_v, const float* __restrict__ b_v,
    const float* __restrict__ w_x,
    unsigned short* __restrict__ qk_t, unsigned short* __restrict__ xv_bf,
    float* __restrict__ xc)
{
    __shared__ __align__(16) unsigned short w_lds[192 * 136];
    __shared__ __align__(16) unsigned short x_t[64 * 136];
    const int tid = threadIdx.x;
    const int wave = tid >> 6, lane = tid & 63;
    const int quad = lane >> 4, col = lane & 15;
    const int b = blockIdx.y;
    const int n0 = blockIdx.x * 64;

    // stage weights: [mat][o][c] -> w_lds[(mat*64+o)*136 + c] (bf16)
    const float* wsrc[3] = {w_qk, w_v, w_x};
    #pragma unroll
    for (int mat = 0; mat < 3; ++mat) {
        const float* wm = wsrc[mat];
        #pragma unroll
        for (int it = 0; it < 8; ++it) {
            const int idx = it * 256 + tid;            // [0, 2048)
            const int o = idx >> 5, c = (idx & 31) * 4;
            const float4 v = *(const float4*)(wm + o * C_ + c);
            us4 pk;
            pk.a = f2bf(v.x); pk.b = f2bf(v.y); pk.c = f2bf(v.z); pk.d = f2bf(v.w);
            *(us4*)&w_lds[(mat * 64 + o) * 136 + c] = pk;
        }
    }
    // stage x tile transposed: x[b][c][n0+n] -> x_t[n*136 + c] (bf16)
    const float* xb = x + (size_t)b * C_ * N_ + n0;
    #pragma unroll
    for (int it = 0; it < 8; ++it) {
        const int idx = it * 256 + tid;                // [0, 2048)
        const int c = idx >> 4, n = (idx & 15) * 4;
        const float4 v = *(const float4*)(xb + (size_t)c * N_ + n);
        x_t[(n + 0) * 136 + c] = f2bf(v.x);
        x_t[(n + 1) * 136 + c] = f2bf(v.y);
        x_t[(n + 2) * 136 + c] = f2bf(v.z);
        x_t[(n + 3) * 136 + c] = f2bf(v.w);
    }
    __syncthreads();

    // B-frags for this wave's 16 n columns (persist across all 12 o-tiles)
    const int nw = wave * 16;
    bf16x8 bfr[4];
    #pragma unroll
    for (int kt = 0; kt < 4; ++kt)
        bfr[kt] = *(const bf16x8*)&x_t[(nw + col) * 136 + kt * 32 + quad * 8];

    const int n_g = n0 + nw + col;   // this lane's global n (D column)

    #pragma unroll
    for (int ot = 0; ot < 12; ++ot) {
        f32x4 acc = {0.f, 0.f, 0.f, 0.f};
        #pragma unroll
        for (int kt = 0; kt < 4; ++kt) {
            const bf16x8 afr = *(const bf16x8*)&w_lds[(ot * 16 + col) * 136 + kt * 32 + quad * 8];
            acc = MFMA16(afr, bfr[kt], acc);
        }
        if (ot < 4) {
            us4 pk;
            pk.a = f2bf(acc[0] * QK_SCALE); pk.b = f2bf(acc[1] * QK_SCALE);
            pk.c = f2bf(acc[2] * QK_SCALE); pk.d = f2bf(acc[3] * QK_SCALE);
            *(us4*)&qk_t[(size_t)(b * N_ + n_g) * C2_ + ot * 16 + quad * 4] = pk;
        } else if (ot < 8) {
            const float4 bv4 = *(const float4*)(b_v + (ot - 4) * 16 + quad * 4);
            const float* bvp = (const float*)&bv4;
            #pragma unroll
            for (int r = 0; r < 4; ++r)
                xv_bf[(size_t)(b * C2_ + (ot - 4) * 16 + quad * 4 + r) * N_ + n_g]
                    = f2bf(acc[r] + bvp[r]);
        } else {
            #pragma unroll
            for (int r = 0; r < 4; ++r)
                xc[(size_t)(b * C2_ + (ot - 8) * 16 + quad * 4 + r) * N_ + n_g] = acc[r];
        }
    }
}

// ---------------------------------------------------------------------------
// K2: partial row softmax sums.  Grid 2048: b=id&7, nblk=(id>>3)&63, mq=id>>9.
//     Each block scans m in [mq*1024, +1024) (16 chunks of 64), accumulating
//     per-lane sum_m 2^E; writes part_rs[mq][b][n].  8 blocks/CU.
// ---------------------------------------------------------------------------
__global__ __launch_bounds__(256) void k2_rowstats(
    const unsigned short* __restrict__ qk_t, float* __restrict__ part_rs)
{
    __shared__ __align__(16) unsigned char lds_raw[2 * 8192];
    const int tid = threadIdx.x;
    const int wave = tid >> 6, lane = tid & 63;
    const int quad = lane >> 4, col = lane & 15;
    const int b = blockIdx.x & 7;
    const int nblk = (blockIdx.x >> 3) & 63;
    const int mq = blockIdx.x >> 9;
    const int n_base = nblk * 64 + wave * 16;
    const int m_start = mq * 1024;
    const unsigned short* qb = qk_t + (size_t)b * N_ * C2_;

    const bf16x8 a0 = *(const bf16x8*)(qb + (size_t)(n_base + col) * C2_ + quad * 8);
    const bf16x8 a1 = *(const bf16x8*)(qb + (size_t)(n_base + col) * C2_ + quad * 8 + 32);

    auto stage = [&](int m0, int p) {
        unsigned char* base = lds_raw + p * 8192;
        #pragma unroll
        for (int r = 0; r < 2; ++r) {
            const int idx = r * 256 + tid;
            const int row = idx >> 3, seg = idx & 7;
            gl_lds16(qb + (size_t)(m0 + row) * C2_ + (size_t)(seg ^ (row & 7)) * 8,
                     base + idx * 16);
        }
    };

    float run_s[4] = {0.f, 0.f, 0.f, 0.f};
    stage(m_start, 0);
    __syncthreads();

    for (int c = 0; c < 16; ++c) {
        const int p = c & 1;
        if (c + 1 < 16) stage(m_start + (c + 1) * 64, 1 - p);
        const unsigned short* qt = (const unsigned short*)(lds_raw + p * 8192);
        #pragma unroll
        for (int ms = 0; ms < 4; ++ms) {
            const int row = ms * 16 + col;
            const bf16x8 b0 = *(const bf16x8*)(qt + row * 64 + ((quad ^ (col & 7)) * 8));
            const bf16x8 b1 = *(const bf16x8*)(qt + row * 64 + (((4 + quad) ^ (col & 7)) * 8));
            f32x4 acc = {0.f, 0.f, 0.f, 0.f};
            acc = MFMA16(a0, b0, acc);
            acc = MFMA16(a1, b1, acc);
            #pragma unroll
            for (int r = 0; r < 4; ++r)
                run_s[r] += __builtin_amdgcn_exp2f(acc[r]);
        }
        __syncthreads();
    }

    #pragma unroll
    for (int r = 0; r < 4; ++r) {
        #pragma unroll
        for (int off = 1; off < 16; off <<= 1)
            run_s[r] += __shfl_xor(run_s[r], off, 64);
    }
    if (col == 0) {
        #pragma unroll
        for (int r = 0; r < 4; ++r)
            part_rs[((size_t)(mq * 8 + b) << 12) + n_base + quad * 4 + r] = run_s[r];
    }
}

// K2b: rowoff[b][n] = log2(sum_q part_rs[q][b][n])
__global__ __launch_bounds__(256) void k2b_comb(
    const float* __restrict__ part_rs, float* __restrict__ rowoff)
{
    const int i = blockIdx.x * 256 + threadIdx.x;   // [0, 32768)
    const int b = i >> 12, n = i & 4095;
    float s = 0.f;
    #pragma unroll
    for (int q = 0; q < 4; ++q)
        s += part_rs[((size_t)(q * 8 + b) << 12) + n];
    rowoff[i] = __builtin_amdgcn_logf(s);
}

// ---------------------------------------------------------------------------
// K3: block owns 128 m-cols (4 waves x 32) and HALF the n-range (split-K).
//     Grid 512: b=id&7, mblk=(id>>3)&31, nh=id>>8.  Per 64-n chunk: stage qk
//     slab + xv tile (global_load_lds dbuf); E = MFMA; S = exp2(E-off) via
//     LDS round-trip; PV MFMA; partial colsum.  Writes partial Y (f32) and
//     partial colsum; k3b combines.  2 blocks/CU overlap barrier stalls.
// ---------------------------------------------------------------------------
__global__ __launch_bounds__(256) void k3_pv(
    const unsigned short* __restrict__ qk_t, const unsigned short* __restrict__ xv_bf,
    const float* __restrict__ rowoff, float* __restrict__ yp0, float* __restrict__ yp1,
    float* __restrict__ cspart)
{
    // 0..16K: qk dbuf | 16K..32K: xv dbuf | 32K..50K: S tiles (4 waves x 2 x 16x72)
    __shared__ __align__(16) unsigned char lds_raw[32768 + 8 * 2304];
    const int tid = threadIdx.x;
    const int wave = tid >> 6, lane = tid & 63;
    const int quad = lane >> 4, col = lane & 15;
    const int b = blockIdx.x & 7;
    const int m_blk = ((blockIdx.x >> 3) & 31) * 128;
    const int nh = blockIdx.x >> 8;                  // 0 or 1
    const int n_start = nh * 2048;
    const int m_wave = m_blk + wave * 32;
    const unsigned short* qb = qk_t + (size_t)b * N_ * C2_;
    const unsigned short* vb = xv_bf + (size_t)b * C2_ * N_;
    const float* ro = rowoff + b * N_;
    float* yp = nh ? yp1 : yp0;

    bf16x8 kb0[2], kb1[2];
    #pragma unroll
    for (int g = 0; g < 2; ++g) {
        const unsigned short* p = qb + (size_t)(m_wave + g * 16 + col) * C2_ + quad * 8;
        kb0[g] = *(const bf16x8*)p;
        kb1[g] = *(const bf16x8*)(p + 32);
    }

    unsigned short (*st_s[2])[72];
    st_s[0] = (unsigned short(*)[72])(lds_raw + 32768 + (wave * 2 + 0) * 2304);
    st_s[1] = (unsigned short(*)[72])(lds_raw + 32768 + (wave * 2 + 1) * 2304);

    auto stage = [&](int n0, int p) {
        unsigned char* qbase = lds_raw + p * 8192;
        unsigned char* vbase = lds_raw + 16384 + p * 8192;
        #pragma unroll
        for (int r = 0; r < 2; ++r) {
            const int idx = r * 256 + tid;
            const int row = idx >> 3, seg = idx & 7;
            const int ss = seg ^ (row & 7);
            gl_lds16(qb + (size_t)(n0 + row) * C2_ + (size_t)ss * 8, qbase + idx * 16);
            gl_lds16(vb + (size_t)row * N_ + n0 + ss * 8, vbase + idx * 16);
        }
    };

    f32x4 accY[2][4];
    #pragma unroll
    for (int g = 0; g < 2; ++g)
        #pragma unroll
        for (int os = 0; os < 4; ++os) accY[g][os] = (f32x4){0.f, 0.f, 0.f, 0.f};
    float colacc[2] = {0.f, 0.f};

    stage(n_start, 0);
    __syncthreads();

    for (int c = 0; c < 32; ++c) {
        const int n0 = n_start + c * 64;
        const int p = c & 1;
        if (c + 1 < 32) stage(n0 + 64, 1 - p);

        float4 ro4[4];
        #pragma unroll
        for (int ns = 0; ns < 4; ++ns)
            ro4[ns] = *(const float4*)(ro + n0 + ns * 16 + quad * 4);

        const unsigned short* qt = (const unsigned short*)(lds_raw + p * 8192);
        const unsigned short* vt = (const unsigned short*)(lds_raw + 16384 + p * 8192);

        #pragma unroll
        for (int ns = 0; ns < 4; ++ns) {
            const int row = ns * 16 + col;
            const bf16x8 qa0 = *(const bf16x8*)(qt + row * 64 + ((quad ^ (col & 7)) * 8));
            const bf16x8 qa1 = *(const bf16x8*)(qt + row * 64 + (((4 + quad) ^ (col & 7)) * 8));
            const float* rr = (const float*)&ro4[ns];
            #pragma unroll
            for (int g = 0; g < 2; ++g) {
                f32x4 acc = {0.f, 0.f, 0.f, 0.f};
                acc = MFMA16(qa0, kb0[g], acc);
                acc = MFMA16(qa1, kb1[g], acc);
                union { unsigned short us[4]; uint2 u2; } pk;
                #pragma unroll
                for (int r = 0; r < 4; ++r) {
                    const float s = __builtin_amdgcn_exp2f(acc[r] - rr[r]);
                    colacc[g] += s;
                    pk.us[r] = f2bf(s);
                }
                *(uint2*)&st_s[g][col][ns * 16 + quad * 4] = pk.u2;
            }
        }

        bf16x8 sB0[2], sB1[2];
        #pragma unroll
        for (int g = 0; g < 2; ++g) {
            sB0[g] = *(const bf16x8*)&st_s[g][col][quad * 8];
            sB1[g] = *(const bf16x8*)&st_s[g][col][32 + quad * 8];
        }
        #pragma unroll
        for (int os = 0; os < 4; ++os) {
            const int o = os * 16 + col;
            const bf16x8 va0 = *(const bf16x8*)(vt + o * 64 + ((quad ^ (col & 7)) * 8));
            const bf16x8 va1 = *(const bf16x8*)(vt + o * 64 + (((4 + quad) ^ (col & 7)) * 8));
            #pragma unroll
            for (int g = 0; g < 2; ++g) {
                accY[g][os] = MFMA16(va0, sB0[g], accY[g][os]);
                accY[g][os] = MFMA16(va1, sB1[g], accY[g][os]);
            }
        }
        __syncthreads();
    }

    #pragma unroll
    for (int g = 0; g < 2; ++g) {
        colacc[g] += __shfl_xor(colacc[g], 16, 64);
        colacc[g] += __shfl_xor(colacc[g], 32, 64);
        if (lane < 16)
            cspart[((size_t)nh * 8 + b) * N_ + m_wave + g * 16 + col] = colacc[g];
        #pragma unroll
        for (int os = 0; os < 4; ++os)
            #pragma unroll
            for (int r = 0; r < 4; ++r)
                yp[(size_t)(b * C2_ + os * 16 + quad * 4 + r) * N_ + m_wave + g * 16 + col]
                    = accY[g][os][r];
    }
}

// K3b: xr = (Y0+Y1) / (1e-9 + cs0+cs1), in-place over the Y0 region.
__global__ __launch_bounds__(256) void k3b_comb(
    float* yp0, const float* __restrict__ yp1,
    const float* __restrict__ cspart)
{
    const int idx4 = blockIdx.x * 256 + threadIdx.x;  // [0, 524288) float4 idx
    const int b = idx4 >> 16;
    const int m4 = idx4 & 1023;
    const float4 y0 = ((const float4*)yp0)[idx4];
    const float4 y1 = ((const float4*)yp1)[idx4];
    const float4 c0 = ((const float4*)cspart)[b * 1024 + m4];
    const float4 c1 = ((const float4*)cspart)[8192 + b * 1024 + m4];
    float4 r;
    r.x = (y0.x + y1.x) / (1e-9f + c0.x + c1.x);
    r.y = (y0.y + y1.y) / (1e-9f + c0.y + c1.y);
    r.z = (y0.z + y1.z) / (1e-9f + c0.z + c1.z);
    r.w = (y0.w + y1.w) / (1e-9f + c0.w + c1.w);
    ((float4*)yp0)[idx4] = r;
}

// ---------------------------------------------------------------------------
// K4: t = w_t @ (xc - xr) + b_t, per (b, 64-n tile).  d-tile + w_t in LDS.
// ---------------------------------------------------------------------------
__global__ __launch_bounds__(256) void k4_t(
    const float* __restrict__ xc, const float* __restrict__ xr,
    const float* __restrict__ w_t, const float* __restrict__ b_t,
    float* __restrict__ t_buf)
{
    __shared__ float d_lds[64][64];
    __shared__ float w_lds[64][64];
    const int b = blockIdx.y;
    const int n0 = blockIdx.x * 64;
    const size_t base = (size_t)b * C2_ * N_;

    for (int idx = threadIdx.x; idx < 4096; idx += 256) {
        const int i = idx >> 6, n = idx & 63;
        const size_t g = base + (size_t)i * N_ + n0 + n;
        d_lds[i][n] = xc[g] - xr[g];
        w_lds[i][n] = w_t[idx];
    }
    __syncthreads();

    const int n = threadIdx.x & 63, ow = (threadIdx.x >> 6) * 16;
    float acc[16];
    #pragma unroll
    for (int oo = 0; oo < 16; ++oo) acc[oo] = 0.f;
    for (int i = 0; i < 64; ++i) {
        const float dv = d_lds[i][n];
        #pragma unroll
        for (int oo = 0; oo < 16; ++oo)
            acc[oo] += w_lds[ow + oo][i] * dv;
    }
    #pragma unroll
    for (int oo = 0; oo < 16; ++oo)
        t_buf[base + (size_t)(ow + oo) * N_ + n0 + n] = acc[oo] + b_t[ow + oo];
}

// ---------------------------------------------------------------------------
// K5: BN batch stats per channel (sum, sumsq over B*N).  One block per o.
// ---------------------------------------------------------------------------
__global__ __launch_bounds__(256) void k5_bnstats(
    const float* __restrict__ t_buf, float* __restrict__ bn)
{
    const int o = blockIdx.x;
    float s = 0.f, s2 = 0.f;
    for (int b = 0; b < B_; ++b) {
        const float4* p = (const float4*)(t_buf + (size_t)(b * C2_ + o) * N_);
        for (int j = threadIdx.x; j < N_ / 4; j += 256) {
            const float4 v = p[j];
            s  += v.x + v.y + v.z + v.w;
            s2 += v.x * v.x + v.y * v.y + v.z * v.z + v.w * v.w;
        }
    }
    #pragma unroll
    for (int off = 1; off < 64; off <<= 1) {
        s  += __shfl_xor(s, off, 64);
        s2 += __shfl_xor(s2, off, 64);
    }
    __shared__ float red[2][4];
    if ((threadIdx.x & 63) == 0) {
        red[0][threadIdx.x >> 6] = s;
        red[1][threadIdx.x >> 6] = s2;
    }
    __syncthreads();
    if (threadIdx.x == 0) {
        bn[o]       = red[0][0] + red[0][1] + red[0][2] + red[0][3];
        bn[64 + o]  = red[1][0] + red[1][1] + red[1][2] + red[1][3];
    }
}

// ---------------------------------------------------------------------------
// K6: out = xc + relu(gamma * (t - mean) * rsqrt(var + eps) + beta)
// ---------------------------------------------------------------------------
__global__ __launch_bounds__(256) void k6_out(
    const float* __restrict__ xc, const float* __restrict__ t_buf,
    const float* __restrict__ bn, const float* __restrict__ gamma,
    const float* __restrict__ beta, float* __restrict__ out)
{
    const int idx = blockIdx.x * 256 + threadIdx.x;
    const int o = (idx >> 10) & 63;
    const float invC = 1.0f / (float)(B_ * N_);
    const float mean = bn[o] * invC;
    const float var  = bn[64 + o] * invC - mean * mean;
    const float sc = gamma[o] * rsqrtf(var + 1e-5f);
    const float sh = beta[o] - mean * sc;
    const float4 t4 = ((const float4*)t_buf)[idx];
    const float4 c4 = ((const float4*)xc)[idx];
    float4 r;
    r.x = c4.x + fmaxf(0.f, sc * t4.x + sh);
    r.y = c4.y + fmaxf(0.f, sc * t4.y + sh);
    r.z = c4.z + fmaxf(0.f, sc * t4.z + sh);
    r.w = c4.w + fmaxf(0.f, sc * t4.w + sh);
    ((float4*)out)[idx] = r;
}

extern "C" void kernel_launch(void* const* d_in, const int* in_sizes, int n_in,
                              void* d_out, int out_size, void* d_ws, size_t ws_size,
                              hipStream_t stream) {
    const float* x     = (const float*)d_in[0];
    const float* w_qk  = (const float*)d_in[1];
    const float* w_v   = (const float*)d_in[2];
    const float* b_v   = (const float*)d_in[3];
    const float* w_x   = (const float*)d_in[4];
    const float* w_t   = (const float*)d_in[5];
    const float* b_t   = (const float*)d_in[6];
    const float* gamma = (const float*)d_in[7];
    const float* beta  = (const float*)d_in[8];
    float* out = (float*)d_out;

    char* ws = (char*)d_ws;
    unsigned short* qk_t  = (unsigned short*)ws;                      // 4 MB
    unsigned short* xv_bf = (unsigned short*)(ws + (4  << 20));       // 4 MB
    float* xc      = (float*)(ws + (8  << 20));                       // 8 MB
    float* xr_yp0  = (float*)(ws + (16 << 20));                       // 8 MB (ypart0 -> xr in place)
    float* tb_yp1  = (float*)(ws + (24 << 20));                       // 8 MB (ypart1, then t_buf)
    float* part_rs = (float*)(ws + (32 << 20));                       // 512 KB
    float* rowoff  = (float*)(ws + (32 << 20) + (512 << 10));         // 128 KB
    float* cspart  = (float*)(ws + (32 << 20) + (640 << 10));         // 256 KB
    float* bn      = (float*)(ws + (32 << 20) + (896 << 10));         // 512 B

    hipLaunchKernelGGL(k1_proj,     dim3(64, 8),  256, 0, stream,
                       x, w_qk, w_v, b_v, w_x, qk_t, xv_bf, xc);
    hipLaunchKernelGGL(k2_rowstats, dim3(2048),   256, 0, stream, qk_t, part_rs);
    hipLaunchKernelGGL(k2b_comb,    dim3(128),    256, 0, stream, part_rs, rowoff);
    hipLaunchKernelGGL(k3_pv,       dim3(512),    256, 0, stream,
                       qk_t, xv_bf, rowoff, xr_yp0, tb_yp1, cspart);
    hipLaunchKernelGGL(k3b_comb,    dim3(2048),   256, 0, stream, xr_yp0, tb_yp1, cspart);
    hipLaunchKernelGGL(k4_t,        dim3(64, 8),  256, 0, stream, xc, xr_yp0, w_t, b_t, tb_yp1);
    hipLaunchKernelGGL(k5_bnstats,  dim3(64),     256, 0, stream, tb_yp1, bn);
    hipLaunchKernelGGL(k6_out,      dim3(2048),   256, 0, stream, xc, tb_yp1, bn, gamma, beta, out);
}

// Round 6
// 196.974 us; speedup vs baseline: 2.6290x; 1.0227x over previous
//
#include <hip/hip_runtime.h>

#define B_   8
#define C_   128
#define N_   4096
#define C2_  64

typedef __bf16 bf16x8 __attribute__((ext_vector_type(8)));
typedef float  f32x4  __attribute__((ext_vector_type(4)));

#define MFMA16(a, b, c) __builtin_amdgcn_mfma_f32_16x16x32_bf16((a), (b), (c), 0, 0, 0)

// sqrt(log2(e)): fold into q/k so softmax uses exp2 directly (E' = E * log2e)
#define QK_SCALE 1.2011224087864498f

static __device__ __forceinline__ unsigned short f2bf(float f) {
    union { __bf16 b; unsigned short u; } cv;
    cv.b = (__bf16)f;
    return cv.u;
}

struct us4 { unsigned short a, b, c, d; };

// async global->LDS, 16 B per lane.  LDS dest must be linear in lane order.
static __device__ __forceinline__ void gl_lds16(const unsigned short* g, void* l) {
    __builtin_amdgcn_global_load_lds(
        (const __attribute__((address_space(1))) unsigned int*)g,
        (__attribute__((address_space(3))) unsigned int*)l,
        16, 0, 0);
}

// ---------------------------------------------------------------------------
// K1: fused projection GEMM.  D[192 o][64 n] = W(3x64 stacked)[o][c] * x[c][n]
//     per (b, 64-n tile).  Weights -> LDS bf16 [192][136]; x tile transposed
//     -> LDS bf16 x_t[64 n][136 c].  Epilogue: ot 0-3 -> qk_t (us4, *QK_SCALE);
//     ot 4-7 -> xv_bf (+b_v); ot 8-11 -> xc (f32).
// ---------------------------------------------------------------------------
__global__ __launch_bounds__(256) void k1_proj(
    const float* __restrict__ x, const float* __restrict__ w_qk,
    const float* __restrict__ w_v, const float* __restrict__ b_v,
    const float* __restrict__ w_x,
    unsigned short* __restrict__ qk_t, unsigned short* __restrict__ xv_bf,
    float* __restrict__ xc)
{
    __shared__ __align__(16) unsigned short w_lds[192 * 136];
    __shared__ __align__(16) unsigned short x_t[64 * 136];
    const int tid = threadIdx.x;
    const int wave = tid >> 6, lane = tid & 63;
    const int quad = lane >> 4, col = lane & 15;
    const int b = blockIdx.y;
    const int n0 = blockIdx.x * 64;

    const float* wsrc[3] = {w_qk, w_v, w_x};
    #pragma unroll
    for (int mat = 0; mat < 3; ++mat) {
        const float* wm = wsrc[mat];
        #pragma unroll
        for (int it = 0; it < 8; ++it) {
            const int idx = it * 256 + tid;            // [0, 2048)
            const int o = idx >> 5, c = (idx & 31) * 4;
            const float4 v = *(const float4*)(wm + o * C_ + c);
            us4 pk;
            pk.a = f2bf(v.x); pk.b = f2bf(v.y); pk.c = f2bf(v.z); pk.d = f2bf(v.w);
            *(us4*)&w_lds[(mat * 64 + o) * 136 + c] = pk;
        }
    }
    const float* xb = x + (size_t)b * C_ * N_ + n0;
    #pragma unroll
    for (int it = 0; it < 8; ++it) {
        const int idx = it * 256 + tid;                // [0, 2048)
        const int c = idx >> 4, n = (idx & 15) * 4;
        const float4 v = *(const float4*)(xb + (size_t)c * N_ + n);
        x_t[(n + 0) * 136 + c] = f2bf(v.x);
        x_t[(n + 1) * 136 + c] = f2bf(v.y);
        x_t[(n + 2) * 136 + c] = f2bf(v.z);
        x_t[(n + 3) * 136 + c] = f2bf(v.w);
    }
    __syncthreads();

    const int nw = wave * 16;
    bf16x8 bfr[4];
    #pragma unroll
    for (int kt = 0; kt < 4; ++kt)
        bfr[kt] = *(const bf16x8*)&x_t[(nw + col) * 136 + kt * 32 + quad * 8];

    const int n_g = n0 + nw + col;

    #pragma unroll
    for (int ot = 0; ot < 12; ++ot) {
        f32x4 acc = {0.f, 0.f, 0.f, 0.f};
        #pragma unroll
        for (int kt = 0; kt < 4; ++kt) {
            const bf16x8 afr = *(const bf16x8*)&w_lds[(ot * 16 + col) * 136 + kt * 32 + quad * 8];
            acc = MFMA16(afr, bfr[kt], acc);
        }
        if (ot < 4) {
            us4 pk;
            pk.a = f2bf(acc[0] * QK_SCALE); pk.b = f2bf(acc[1] * QK_SCALE);
            pk.c = f2bf(acc[2] * QK_SCALE); pk.d = f2bf(acc[3] * QK_SCALE);
            *(us4*)&qk_t[(size_t)(b * N_ + n_g) * C2_ + ot * 16 + quad * 4] = pk;
        } else if (ot < 8) {
            const float4 bv4 = *(const float4*)(b_v + (ot - 4) * 16 + quad * 4);
            const float* bvp = (const float*)&bv4;
            #pragma unroll
            for (int r = 0; r < 4; ++r)
                xv_bf[(size_t)(b * C2_ + (ot - 4) * 16 + quad * 4 + r) * N_ + n_g]
                    = f2bf(acc[r] + bvp[r]);
        } else {
            #pragma unroll
            for (int r = 0; r < 4; ++r)
                xc[(size_t)(b * C2_ + (ot - 8) * 16 + quad * 4 + r) * N_ + n_g] = acc[r];
        }
    }
}

// ---------------------------------------------------------------------------
// K2: partial row softmax sums.  Grid 1024: b=id&7, nblk=(id>>3)&31, mq=id>>8.
//     Wave owns 32 n-rows (two A-frag sets); block owns 128 rows x 1024 m
//     (16 chunks of 64).  Staged B-slab shared by 2x the compute vs r5.
//     Writes part_rs[mq][b][n].  4 blocks/CU.
// ---------------------------------------------------------------------------
__global__ __launch_bounds__(256) void k2_rowstats(
    const unsigned short* __restrict__ qk_t, float* __restrict__ part_rs)
{
    __shared__ __align__(16) unsigned char lds_raw[2 * 8192];
    const int tid = threadIdx.x;
    const int wave = tid >> 6, lane = tid & 63;
    const int quad = lane >> 4, col = lane & 15;
    const int b = blockIdx.x & 7;
    const int nblk = (blockIdx.x >> 3) & 31;
    const int mq = blockIdx.x >> 8;                   // 0..3
    const int n_base = nblk * 128 + wave * 32;
    const int m_start = mq * 1024;
    const unsigned short* qb = qk_t + (size_t)b * N_ * C2_;

    // two persistent A-frag sets: rows [n_base, +16) and [n_base+16, +32)
    bf16x8 a0[2], a1[2];
    #pragma unroll
    for (int s = 0; s < 2; ++s) {
        const unsigned short* p = qb + (size_t)(n_base + s * 16 + col) * C2_ + quad * 8;
        a0[s] = *(const bf16x8*)p;
        a1[s] = *(const bf16x8*)(p + 32);
    }

    auto stage = [&](int m0, int p) {
        unsigned char* base = lds_raw + p * 8192;
        #pragma unroll
        for (int r = 0; r < 2; ++r) {
            const int idx = r * 256 + tid;
            const int row = idx >> 3, seg = idx & 7;
            gl_lds16(qb + (size_t)(m0 + row) * C2_ + (size_t)(seg ^ (row & 7)) * 8,
                     base + idx * 16);
        }
    };

    float run_s[2][4] = {{0.f, 0.f, 0.f, 0.f}, {0.f, 0.f, 0.f, 0.f}};
    stage(m_start, 0);
    __syncthreads();

    for (int c = 0; c < 16; ++c) {
        const int p = c & 1;
        if (c + 1 < 16) stage(m_start + (c + 1) * 64, 1 - p);
        const unsigned short* qt = (const unsigned short*)(lds_raw + p * 8192);
        #pragma unroll
        for (int ms = 0; ms < 4; ++ms) {
            const int row = ms * 16 + col;
            const bf16x8 b0 = *(const bf16x8*)(qt + row * 64 + ((quad ^ (col & 7)) * 8));
            const bf16x8 b1 = *(const bf16x8*)(qt + row * 64 + (((4 + quad) ^ (col & 7)) * 8));
            #pragma unroll
            for (int s = 0; s < 2; ++s) {
                f32x4 acc = {0.f, 0.f, 0.f, 0.f};
                acc = MFMA16(a0[s], b0, acc);
                acc = MFMA16(a1[s], b1, acc);
                #pragma unroll
                for (int r = 0; r < 4; ++r)
                    run_s[s][r] += __builtin_amdgcn_exp2f(acc[r]);
            }
        }
        __syncthreads();
    }

    #pragma unroll
    for (int s = 0; s < 2; ++s)
        #pragma unroll
        for (int r = 0; r < 4; ++r) {
            #pragma unroll
            for (int off = 1; off < 16; off <<= 1)
                run_s[s][r] += __shfl_xor(run_s[s][r], off, 64);
        }
    if (col == 0) {
        #pragma unroll
        for (int s = 0; s < 2; ++s)
            #pragma unroll
            for (int r = 0; r < 4; ++r)
                part_rs[((size_t)(mq * 8 + b) << 12) + n_base + s * 16 + quad * 4 + r]
                    = run_s[s][r];
    }
}

// K2b: rowoff[b][n] = log2(sum_q part_rs[q][b][n])
__global__ __launch_bounds__(256) void k2b_comb(
    const float* __restrict__ part_rs, float* __restrict__ rowoff)
{
    const int i = blockIdx.x * 256 + threadIdx.x;   // [0, 32768)
    const int b = i >> 12, n = i & 4095;
    float s = 0.f;
    #pragma unroll
    for (int q = 0; q < 4; ++q)
        s += part_rs[((size_t)(q * 8 + b) << 12) + n];
    rowoff[i] = __builtin_amdgcn_logf(s);
}

// ---------------------------------------------------------------------------
// K3: block owns 128 m-cols (4 waves x 32) and a THIRD of the n-range.
//     Grid 768: b=id&7, mblk=(id>>3)&31, s=id>>8 (0..2).  3 blocks/CU.
//     Per 64-n chunk: stage qk slab + xv tile (global_load_lds dbuf);
//     E = MFMA; S = exp2(E-off) via LDS round-trip; PV MFMA; partial colsum.
//     Writes partial Y (f32, yp[s]) + partial colsum; k3b combines.
// ---------------------------------------------------------------------------
__global__ __launch_bounds__(256) void k3_pv(
    const unsigned short* __restrict__ qk_t, const unsigned short* __restrict__ xv_bf,
    const float* __restrict__ rowoff, float* __restrict__ yp0, float* __restrict__ yp1,
    float* __restrict__ yp2, float* __restrict__ cspart)
{
    // 0..16K: qk dbuf | 16K..32K: xv dbuf | 32K..50K: S tiles (4 waves x 2 x 16x72)
    __shared__ __align__(16) unsigned char lds_raw[32768 + 8 * 2304];
    const int tid = threadIdx.x;
    const int wave = tid >> 6, lane = tid & 63;
    const int quad = lane >> 4, col = lane & 15;
    const int b = blockIdx.x & 7;
    const int m_blk = ((blockIdx.x >> 3) & 31) * 128;
    const int sk = blockIdx.x >> 8;                  // 0..2 (split-K index)
    const int n_start = (sk == 0) ? 0 : 1408 + (sk - 1) * 1344;
    const int n_chunks = (sk == 0) ? 22 : 21;
    const int m_wave = m_blk + wave * 32;
    const unsigned short* qb = qk_t + (size_t)b * N_ * C2_;
    const unsigned short* vb = xv_bf + (size_t)b * C2_ * N_;
    const float* ro = rowoff + b * N_;
    float* yp = (sk == 0) ? yp0 : (sk == 1) ? yp1 : yp2;

    bf16x8 kb0[2], kb1[2];
    #pragma unroll
    for (int g = 0; g < 2; ++g) {
        const unsigned short* p = qb + (size_t)(m_wave + g * 16 + col) * C2_ + quad * 8;
        kb0[g] = *(const bf16x8*)p;
        kb1[g] = *(const bf16x8*)(p + 32);
    }

    unsigned short (*st_s[2])[72];
    st_s[0] = (unsigned short(*)[72])(lds_raw + 32768 + (wave * 2 + 0) * 2304);
    st_s[1] = (unsigned short(*)[72])(lds_raw + 32768 + (wave * 2 + 1) * 2304);

    auto stage = [&](int n0, int p) {
        unsigned char* qbase = lds_raw + p * 8192;
        unsigned char* vbase = lds_raw + 16384 + p * 8192;
        #pragma unroll
        for (int r = 0; r < 2; ++r) {
            const int idx = r * 256 + tid;
            const int row = idx >> 3, seg = idx & 7;
            const int ss = seg ^ (row & 7);
            gl_lds16(qb + (size_t)(n0 + row) * C2_ + (size_t)ss * 8, qbase + idx * 16);
            gl_lds16(vb + (size_t)row * N_ + n0 + ss * 8, vbase + idx * 16);
        }
    };

    f32x4 accY[2][4];
    #pragma unroll
    for (int g = 0; g < 2; ++g)
        #pragma unroll
        for (int os = 0; os < 4; ++os) accY[g][os] = (f32x4){0.f, 0.f, 0.f, 0.f};
    float colacc[2] = {0.f, 0.f};

    stage(n_start, 0);
    __syncthreads();

    for (int c = 0; c < n_chunks; ++c) {
        const int n0 = n_start + c * 64;
        const int p = c & 1;
        if (c + 1 < n_chunks) stage(n0 + 64, 1 - p);

        float4 ro4[4];
        #pragma unroll
        for (int ns = 0; ns < 4; ++ns)
            ro4[ns] = *(const float4*)(ro + n0 + ns * 16 + quad * 4);

        const unsigned short* qt = (const unsigned short*)(lds_raw + p * 8192);
        const unsigned short* vt = (const unsigned short*)(lds_raw + 16384 + p * 8192);

        #pragma unroll
        for (int ns = 0; ns < 4; ++ns) {
            const int row = ns * 16 + col;
            const bf16x8 qa0 = *(const bf16x8*)(qt + row * 64 + ((quad ^ (col & 7)) * 8));
            const bf16x8 qa1 = *(const bf16x8*)(qt + row * 64 + (((4 + quad) ^ (col & 7)) * 8));
            const float* rr = (const float*)&ro4[ns];
            #pragma unroll
            for (int g = 0; g < 2; ++g) {
                f32x4 acc = {0.f, 0.f, 0.f, 0.f};
                acc = MFMA16(qa0, kb0[g], acc);
                acc = MFMA16(qa1, kb1[g], acc);
                union { unsigned short us[4]; uint2 u2; } pk;
                #pragma unroll
                for (int r = 0; r < 4; ++r) {
                    const float s = __builtin_amdgcn_exp2f(acc[r] - rr[r]);
                    colacc[g] += s;
                    pk.us[r] = f2bf(s);
                }
                *(uint2*)&st_s[g][col][ns * 16 + quad * 4] = pk.u2;
            }
        }

        bf16x8 sB0[2], sB1[2];
        #pragma unroll
        for (int g = 0; g < 2; ++g) {
            sB0[g] = *(const bf16x8*)&st_s[g][col][quad * 8];
            sB1[g] = *(const bf16x8*)&st_s[g][col][32 + quad * 8];
        }
        #pragma unroll
        for (int os = 0; os < 4; ++os) {
            const int o = os * 16 + col;
            const bf16x8 va0 = *(const bf16x8*)(vt + o * 64 + ((quad ^ (col & 7)) * 8));
            const bf16x8 va1 = *(const bf16x8*)(vt + o * 64 + (((4 + quad) ^ (col & 7)) * 8));
            #pragma unroll
            for (int g = 0; g < 2; ++g) {
                accY[g][os] = MFMA16(va0, sB0[g], accY[g][os]);
                accY[g][os] = MFMA16(va1, sB1[g], accY[g][os]);
            }
        }
        __syncthreads();
    }

    #pragma unroll
    for (int g = 0; g < 2; ++g) {
        colacc[g] += __shfl_xor(colacc[g], 16, 64);
        colacc[g] += __shfl_xor(colacc[g], 32, 64);
        if (lane < 16)
            cspart[((size_t)sk * 8 + b) * N_ + m_wave + g * 16 + col] = colacc[g];
        #pragma unroll
        for (int os = 0; os < 4; ++os)
            #pragma unroll
            for (int r = 0; r < 4; ++r)
                yp[(size_t)(b * C2_ + os * 16 + quad * 4 + r) * N_ + m_wave + g * 16 + col]
                    = accY[g][os][r];
    }
}

// K3b: xr = (Y0+Y1+Y2) / (1e-9 + cs0+cs1+cs2), in-place over the Y0 region.
__global__ __launch_bounds__(256) void k3b_comb(
    float* yp0, const float* __restrict__ yp1, const float* __restrict__ yp2,
    const float* __restrict__ cspart)
{
    const int idx4 = blockIdx.x * 256 + threadIdx.x;  // [0, 524288) float4 idx
    const int b = idx4 >> 16;
    const int m4 = idx4 & 1023;
    const float4 y0 = ((const float4*)yp0)[idx4];
    const float4 y1 = ((const float4*)yp1)[idx4];
    const float4 y2 = ((const float4*)yp2)[idx4];
    const float4 c0 = ((const float4*)cspart)[b * 1024 + m4];
    const float4 c1 = ((const float4*)cspart)[8192 + b * 1024 + m4];
    const float4 c2 = ((const float4*)cspart)[16384 + b * 1024 + m4];
    float4 r;
    r.x = (y0.x + y1.x + y2.x) / (1e-9f + c0.x + c1.x + c2.x);
    r.y = (y0.y + y1.y + y2.y) / (1e-9f + c0.y + c1.y + c2.y);
    r.z = (y0.z + y1.z + y2.z) / (1e-9f + c0.z + c1.z + c2.z);
    r.w = (y0.w + y1.w + y2.w) / (1e-9f + c0.w + c1.w + c2.w);
    ((float4*)yp0)[idx4] = r;
}

// ---------------------------------------------------------------------------
// K4: t = w_t @ (xc - xr) + b_t, per (b, 64-n tile).  d-tile + w_t in LDS.
// ---------------------------------------------------------------------------
__global__ __launch_bounds__(256) void k4_t(
    const float* __restrict__ xc, const float* __restrict__ xr,
    const float* __restrict__ w_t, const float* __restrict__ b_t,
    float* __restrict__ t_buf)
{
    __shared__ float d_lds[64][64];
    __shared__ float w_lds[64][64];
    const int b = blockIdx.y;
    const int n0 = blockIdx.x * 64;
    const size_t base = (size_t)b * C2_ * N_;

    for (int idx = threadIdx.x; idx < 4096; idx += 256) {
        const int i = idx >> 6, n = idx & 63;
        const size_t g = base + (size_t)i * N_ + n0 + n;
        d_lds[i][n] = xc[g] - xr[g];
        w_lds[i][n] = w_t[idx];
    }
    __syncthreads();

    const int n = threadIdx.x & 63, ow = (threadIdx.x >> 6) * 16;
    float acc[16];
    #pragma unroll
    for (int oo = 0; oo < 16; ++oo) acc[oo] = 0.f;
    for (int i = 0; i < 64; ++i) {
        const float dv = d_lds[i][n];
        #pragma unroll
        for (int oo = 0; oo < 16; ++oo)
            acc[oo] += w_lds[ow + oo][i] * dv;
    }
    #pragma unroll
    for (int oo = 0; oo < 16; ++oo)
        t_buf[base + (size_t)(ow + oo) * N_ + n0 + n] = acc[oo] + b_t[ow + oo];
}

// ---------------------------------------------------------------------------
// K5: BN batch stats per channel (sum, sumsq over B*N).  One block per o.
// ---------------------------------------------------------------------------
__global__ __launch_bounds__(256) void k5_bnstats(
    const float* __restrict__ t_buf, float* __restrict__ bn)
{
    const int o = blockIdx.x;
    float s = 0.f, s2 = 0.f;
    for (int b = 0; b < B_; ++b) {
        const float4* p = (const float4*)(t_buf + (size_t)(b * C2_ + o) * N_);
        for (int j = threadIdx.x; j < N_ / 4; j += 256) {
            const float4 v = p[j];
            s  += v.x + v.y + v.z + v.w;
            s2 += v.x * v.x + v.y * v.y + v.z * v.z + v.w * v.w;
        }
    }
    #pragma unroll
    for (int off = 1; off < 64; off <<= 1) {
        s  += __shfl_xor(s, off, 64);
        s2 += __shfl_xor(s2, off, 64);
    }
    __shared__ float red[2][4];
    if ((threadIdx.x & 63) == 0) {
        red[0][threadIdx.x >> 6] = s;
        red[1][threadIdx.x >> 6] = s2;
    }
    __syncthreads();
    if (threadIdx.x == 0) {
        bn[o]       = red[0][0] + red[0][1] + red[0][2] + red[0][3];
        bn[64 + o]  = red[1][0] + red[1][1] + red[1][2] + red[1][3];
    }
}

// ---------------------------------------------------------------------------
// K6: out = xc + relu(gamma * (t - mean) * rsqrt(var + eps) + beta)
// ---------------------------------------------------------------------------
__global__ __launch_bounds__(256) void k6_out(
    const float* __restrict__ xc, const float* __restrict__ t_buf,
    const float* __restrict__ bn, const float* __restrict__ gamma,
    const float* __restrict__ beta, float* __restrict__ out)
{
    const int idx = blockIdx.x * 256 + threadIdx.x;
    const int o = (idx >> 10) & 63;
    const float invC = 1.0f / (float)(B_ * N_);
    const float mean = bn[o] * invC;
    const float var  = bn[64 + o] * invC - mean * mean;
    const float sc = gamma[o] * rsqrtf(var + 1e-5f);
    const float sh = beta[o] - mean * sc;
    const float4 t4 = ((const float4*)t_buf)[idx];
    const float4 c4 = ((const float4*)xc)[idx];
    float4 r;
    r.x = c4.x + fmaxf(0.f, sc * t4.x + sh);
    r.y = c4.y + fmaxf(0.f, sc * t4.y + sh);
    r.z = c4.z + fmaxf(0.f, sc * t4.z + sh);
    r.w = c4.w + fmaxf(0.f, sc * t4.w + sh);
    ((float4*)out)[idx] = r;
}

extern "C" void kernel_launch(void* const* d_in, const int* in_sizes, int n_in,
                              void* d_out, int out_size, void* d_ws, size_t ws_size,
                              hipStream_t stream) {
    const float* x     = (const float*)d_in[0];
    const float* w_qk  = (const float*)d_in[1];
    const float* w_v   = (const float*)d_in[2];
    const float* b_v   = (const float*)d_in[3];
    const float* w_x   = (const float*)d_in[4];
    const float* w_t   = (const float*)d_in[5];
    const float* b_t   = (const float*)d_in[6];
    const float* gamma = (const float*)d_in[7];
    const float* beta  = (const float*)d_in[8];
    float* out = (float*)d_out;

    char* ws = (char*)d_ws;
    unsigned short* qk_t  = (unsigned short*)ws;                      // 4 MB
    unsigned short* xv_bf = (unsigned short*)(ws + (4  << 20));       // 4 MB
    float* xc      = (float*)(ws + (8  << 20));                       // 8 MB
    float* xr_yp0  = (float*)(ws + (16 << 20));                       // 8 MB (ypart0 -> xr in place)
    float* tb_yp1  = (float*)(ws + (24 << 20));                       // 8 MB (ypart1, then t_buf)
    float* part_rs = (float*)(ws + (32 << 20));                       // 512 KB
    float* rowoff  = (float*)(ws + (32 << 20) + (512 << 10));         // 128 KB
    float* cspart  = (float*)(ws + (32 << 20) + (640 << 10));         // 384 KB
    float* bn      = (float*)(ws + (33 << 20));                       // 512 B
    float* yp2     = out;                                             // 8 MB scratch until k3b

    hipLaunchKernelGGL(k1_proj,     dim3(64, 8),  256, 0, stream,
                       x, w_qk, w_v, b_v, w_x, qk_t, xv_bf, xc);
    hipLaunchKernelGGL(k2_rowstats, dim3(1024),   256, 0, stream, qk_t, part_rs);
    hipLaunchKernelGGL(k2b_comb,    dim3(128),    256, 0, stream, part_rs, rowoff);
    hipLaunchKernelGGL(k3_pv,       dim3(768),    256, 0, stream,
                       qk_t, xv_bf, rowoff, xr_yp0, tb_yp1, yp2, cspart);
    hipLaunchKernelGGL(k3b_comb,    dim3(2048),   256, 0, stream, xr_yp0, tb_yp1, yp2, cspart);
    hipLaunchKernelGGL(k4_t,        dim3(64, 8),  256, 0, stream, xc, xr_yp0, w_t, b_t, tb_yp1);
    hipLaunchKernelGGL(k5_bnstats,  dim3(64),     256, 0, stream, tb_yp1, bn);
    hipLaunchKernelGGL(k6_out,      dim3(2048),   256, 0, stream, xc, tb_yp1, bn, gamma, beta, out);
}

// Round 7
// 192.695 us; speedup vs baseline: 2.6874x; 1.0222x over previous
//
#include <hip/hip_runtime.h>

#define B_   8
#define C_   128
#define N_   4096
#define C2_  64

typedef __bf16 bf16x8 __attribute__((ext_vector_type(8)));
typedef float  f32x4  __attribute__((ext_vector_type(4)));

#define MFMA16(a, b, c) __builtin_amdgcn_mfma_f32_16x16x32_bf16((a), (b), (c), 0, 0, 0)

// sqrt(log2(e)): fold into q/k so softmax uses exp2 directly (E' = E * log2e)
#define QK_SCALE 1.2011224087864498f

static __device__ __forceinline__ unsigned short f2bf(float f) {
    union { __bf16 b; unsigned short u; } cv;
    cv.b = (__bf16)f;
    return cv.u;
}
static __device__ __forceinline__ float bf2f(unsigned short u) {
    union { unsigned int u; float f; } cv;
    cv.u = ((unsigned int)u) << 16;
    return cv.f;
}

struct us4 { unsigned short a, b, c, d; };

// async global->LDS, 16 B per lane.  LDS dest must be linear in lane order.
static __device__ __forceinline__ void gl_lds16(const unsigned short* g, void* l) {
    __builtin_amdgcn_global_load_lds(
        (const __attribute__((address_space(1))) unsigned int*)g,
        (__attribute__((address_space(3))) unsigned int*)l,
        16, 0, 0);
}

// ---------------------------------------------------------------------------
// K1: fused projection GEMM.  D[192 o][64 n] = W(3x64 stacked)[o][c] * x[c][n]
//     per (b, 64-n tile).  Weights -> LDS bf16 [192][136]; x tile transposed
//     -> LDS bf16 x_t[64 n][136 c].  Epilogue: ot 0-3 -> qk_t (us4, *QK_SCALE);
//     ot 4-7 -> xv_bf (+b_v); ot 8-11 -> xc (f32).
// ---------------------------------------------------------------------------
__global__ __launch_bounds__(256) void k1_proj(
    const float* __restrict__ x, const float* __restrict__ w_qk,
    const float* __restrict__ w_v, const float* __restrict__ b_v,
    const float* __restrict__ w_x,
    unsigned short* __restrict__ qk_t, unsigned short* __restrict__ xv_bf,
    float* __restrict__ xc)
{
    __shared__ __align__(16) unsigned short w_lds[192 * 136];
    __shared__ __align__(16) unsigned short x_t[64 * 136];
    const int tid = threadIdx.x;
    const int wave = tid >> 6, lane = tid & 63;
    const int quad = lane >> 4, col = lane & 15;
    const int b = blockIdx.y;
    const int n0 = blockIdx.x * 64;

    const float* wsrc[3] = {w_qk, w_v, w_x};
    #pragma unroll
    for (int mat = 0; mat < 3; ++mat) {
        const float* wm = wsrc[mat];
        #pragma unroll
        for (int it = 0; it < 8; ++it) {
            const int idx = it * 256 + tid;            // [0, 2048)
            const int o = idx >> 5, c = (idx & 31) * 4;
            const float4 v = *(const float4*)(wm + o * C_ + c);
            us4 pk;
            pk.a = f2bf(v.x); pk.b = f2bf(v.y); pk.c = f2bf(v.z); pk.d = f2bf(v.w);
            *(us4*)&w_lds[(mat * 64 + o) * 136 + c] = pk;
        }
    }
    const float* xb = x + (size_t)b * C_ * N_ + n0;
    #pragma unroll
    for (int it = 0; it < 8; ++it) {
        const int idx = it * 256 + tid;                // [0, 2048)
        const int c = idx >> 4, n = (idx & 15) * 4;
        const float4 v = *(const float4*)(xb + (size_t)c * N_ + n);
        x_t[(n + 0) * 136 + c] = f2bf(v.x);
        x_t[(n + 1) * 136 + c] = f2bf(v.y);
        x_t[(n + 2) * 136 + c] = f2bf(v.z);
        x_t[(n + 3) * 136 + c] = f2bf(v.w);
    }
    __syncthreads();

    const int nw = wave * 16;
    bf16x8 bfr[4];
    #pragma unroll
    for (int kt = 0; kt < 4; ++kt)
        bfr[kt] = *(const bf16x8*)&x_t[(nw + col) * 136 + kt * 32 + quad * 8];

    const int n_g = n0 + nw + col;

    #pragma unroll
    for (int ot = 0; ot < 12; ++ot) {
        f32x4 acc = {0.f, 0.f, 0.f, 0.f};
        #pragma unroll
        for (int kt = 0; kt < 4; ++kt) {
            const bf16x8 afr = *(const bf16x8*)&w_lds[(ot * 16 + col) * 136 + kt * 32 + quad * 8];
            acc = MFMA16(afr, bfr[kt], acc);
        }
        if (ot < 4) {
            us4 pk;
            pk.a = f2bf(acc[0] * QK_SCALE); pk.b = f2bf(acc[1] * QK_SCALE);
            pk.c = f2bf(acc[2] * QK_SCALE); pk.d = f2bf(acc[3] * QK_SCALE);
            *(us4*)&qk_t[(size_t)(b * N_ + n_g) * C2_ + ot * 16 + quad * 4] = pk;
        } else if (ot < 8) {
            const float4 bv4 = *(const float4*)(b_v + (ot - 4) * 16 + quad * 4);
            const float* bvp = (const float*)&bv4;
            #pragma unroll
            for (int r = 0; r < 4; ++r)
                xv_bf[(size_t)(b * C2_ + (ot - 4) * 16 + quad * 4 + r) * N_ + n_g]
                    = f2bf(acc[r] + bvp[r]);
        } else {
            #pragma unroll
            for (int r = 0; r < 4; ++r)
                xc[(size_t)(b * C2_ + (ot - 8) * 16 + quad * 4 + r) * N_ + n_g] = acc[r];
        }
    }
}

// ---------------------------------------------------------------------------
// K2: partial row softmax sums.  Grid 1024: b=id&7, nblk=(id>>3)&15, mq=id>>7.
//     Wave owns 64 n-rows (4 A-frag sets); block owns 256 rows x 512 m
//     (8 chunks of 64).  Staged B-slab amortized 4x.  Writes part_rs[mq][b][n].
// ---------------------------------------------------------------------------
__global__ __launch_bounds__(256) void k2_rowstats(
    const unsigned short* __restrict__ qk_t, float* __restrict__ part_rs)
{
    __shared__ __align__(16) unsigned char lds_raw[2 * 8192];
    const int tid = threadIdx.x;
    const int wave = tid >> 6, lane = tid & 63;
    const int quad = lane >> 4, col = lane & 15;
    const int b = blockIdx.x & 7;
    const int nblk = (blockIdx.x >> 3) & 15;
    const int mq = blockIdx.x >> 7;                   // 0..7
    const int n_base = nblk * 256 + wave * 64;
    const int m_start = mq * 512;
    const unsigned short* qb = qk_t + (size_t)b * N_ * C2_;

    // four persistent A-frag sets: rows n_base + s*16 + col
    bf16x8 a0[4], a1[4];
    #pragma unroll
    for (int s = 0; s < 4; ++s) {
        const unsigned short* p = qb + (size_t)(n_base + s * 16 + col) * C2_ + quad * 8;
        a0[s] = *(const bf16x8*)p;
        a1[s] = *(const bf16x8*)(p + 32);
    }

    auto stage = [&](int m0, int p) {
        unsigned char* base = lds_raw + p * 8192;
        #pragma unroll
        for (int r = 0; r < 2; ++r) {
            const int idx = r * 256 + tid;
            const int row = idx >> 3, seg = idx & 7;
            gl_lds16(qb + (size_t)(m0 + row) * C2_ + (size_t)(seg ^ (row & 7)) * 8,
                     base + idx * 16);
        }
    };

    float run_s[4][4];
    #pragma unroll
    for (int s = 0; s < 4; ++s)
        #pragma unroll
        for (int r = 0; r < 4; ++r) run_s[s][r] = 0.f;

    stage(m_start, 0);
    __syncthreads();

    for (int c = 0; c < 8; ++c) {
        const int p = c & 1;
        if (c + 1 < 8) stage(m_start + (c + 1) * 64, 1 - p);
        const unsigned short* qt = (const unsigned short*)(lds_raw + p * 8192);
        #pragma unroll
        for (int ms = 0; ms < 4; ++ms) {
            const int row = ms * 16 + col;
            const bf16x8 b0 = *(const bf16x8*)(qt + row * 64 + ((quad ^ (col & 7)) * 8));
            const bf16x8 b1 = *(const bf16x8*)(qt + row * 64 + (((4 + quad) ^ (col & 7)) * 8));
            #pragma unroll
            for (int s = 0; s < 4; ++s) {
                f32x4 acc = {0.f, 0.f, 0.f, 0.f};
                acc = MFMA16(a0[s], b0, acc);
                acc = MFMA16(a1[s], b1, acc);
                #pragma unroll
                for (int r = 0; r < 4; ++r)
                    run_s[s][r] += __builtin_amdgcn_exp2f(acc[r]);
            }
        }
        __syncthreads();
    }

    #pragma unroll
    for (int s = 0; s < 4; ++s)
        #pragma unroll
        for (int r = 0; r < 4; ++r) {
            #pragma unroll
            for (int off = 1; off < 16; off <<= 1)
                run_s[s][r] += __shfl_xor(run_s[s][r], off, 64);
        }
    if (col == 0) {
        #pragma unroll
        for (int s = 0; s < 4; ++s)
            #pragma unroll
            for (int r = 0; r < 4; ++r)
                part_rs[((size_t)(mq * 8 + b) << 12) + n_base + s * 16 + quad * 4 + r]
                    = run_s[s][r];
    }
}

// K2b: winv[b][n] = 1/rowsum; wbf = bf16(winv)
__global__ __launch_bounds__(256) void k2b_comb(
    const float* __restrict__ part_rs, float* __restrict__ winv,
    unsigned short* __restrict__ wbf)
{
    const int i = blockIdx.x * 256 + threadIdx.x;   // [0, 32768)
    const int b = i >> 12, n = i & 4095;
    float s = 0.f;
    #pragma unroll
    for (int q = 0; q < 8; ++q)
        s += part_rs[((size_t)(q * 8 + b) << 12) + n];
    const float w = 1.0f / s;
    winv[i] = w;
    wbf[i] = f2bf(w);
}

// K2c: xv_bf[b][o][n] *= winv[b][n]  (in place; folds softmax row-normalizer)
__global__ __launch_bounds__(256) void k2c_scale(
    unsigned short* __restrict__ xv_bf, const float* __restrict__ winv)
{
    const int t = blockIdx.x * 256 + threadIdx.x;   // [0, 524288)
    const int flat = t * 4;
    const int b = flat >> 18;                        // /(64*4096)
    const int n = flat & 4095;
    const float4 w4 = *(const float4*)(winv + b * 4096 + n);
    us4 v = *(us4*)(xv_bf + flat);
    v.a = f2bf(bf2f(v.a) * w4.x);
    v.b = f2bf(bf2f(v.b) * w4.y);
    v.c = f2bf(bf2f(v.c) * w4.z);
    v.d = f2bf(bf2f(v.d) * w4.w);
    *(us4*)(xv_bf + flat) = v;
}

// ---------------------------------------------------------------------------
// K3: block owns 128 m-cols and a THIRD of n (split-K, grid 768, 3 blk/CU).
//     Waves: (m-half mh, n-half nh2).  Per 64-n chunk: stage qk slab + xv tile
//     (dbuf DMA); each wave computes E for its 32 n x 64 m; S' = exp2(E)
//     (row-normalizer pre-folded into xv); LDS round-trip; PV MFMA + colsum
//     MFMA (A-rows = wbf).  Epilogue: cross n-half combine in LDS; write
//     partial Y + partial colsum; k3b combines the 3 splits.
// ---------------------------------------------------------------------------
__global__ __launch_bounds__(256, 3) void k3_pv(
    const unsigned short* __restrict__ qk_t, const unsigned short* __restrict__ xv_bf,
    const unsigned short* __restrict__ wbf,
    float* __restrict__ yp0, float* __restrict__ yp1, float* __restrict__ yp2,
    float* __restrict__ cspart)
{
    // 0..16K: qk dbuf | 16K..32K: xv dbuf | 32K..52K: S tiles (4 waves x [4g][16][40])
    __shared__ __align__(16) unsigned char lds_raw[32768 + 4 * 5120];
    const int tid = threadIdx.x;
    const int wave = tid >> 6, lane = tid & 63;
    const int quad = lane >> 4, col = lane & 15;
    const int nh2 = wave & 1, mh = wave >> 1;
    const int b = blockIdx.x & 7;
    const int m_blk = ((blockIdx.x >> 3) & 31) * 128;
    const int sk = blockIdx.x >> 8;                  // 0..2 (split-K index)
    const int n_start = (sk == 0) ? 0 : 1408 + (sk - 1) * 1344;
    const int n_chunks = (sk == 0) ? 22 : 21;
    const int m_wave = m_blk + mh * 64;
    const unsigned short* qb = qk_t + (size_t)b * N_ * C2_;
    const unsigned short* vb = xv_bf + (size_t)b * C2_ * N_;
    const unsigned short* wb = wbf + b * N_;
    float* yp = (sk == 0) ? yp0 : (sk == 1) ? yp1 : yp2;

    // persistent B-operands for E: this wave's 64 m-cols (4 groups of 16)
    bf16x8 kb0[4], kb1[4];
    #pragma unroll
    for (int g = 0; g < 4; ++g) {
        const unsigned short* p = qb + (size_t)(m_wave + g * 16 + col) * C2_ + quad * 8;
        kb0[g] = *(const bf16x8*)p;
        kb1[g] = *(const bf16x8*)(p + 32);
    }

    unsigned short* stS = (unsigned short*)(lds_raw + 32768 + wave * 5120); // [g][col][40]

    auto stage = [&](int n0, int p) {
        unsigned char* qbase = lds_raw + p * 8192;
        unsigned char* vbase = lds_raw + 16384 + p * 8192;
        #pragma unroll
        for (int r = 0; r < 2; ++r) {
            const int idx = r * 256 + tid;
            const int row = idx >> 3, seg = idx & 7;
            const int ss = seg ^ (row & 7);
            gl_lds16(qb + (size_t)(n0 + row) * C2_ + (size_t)ss * 8, qbase + idx * 16);
            gl_lds16(vb + (size_t)row * N_ + n0 + ss * 8, vbase + idx * 16);
        }
    };

    f32x4 accY[4][4];
    #pragma unroll
    for (int g = 0; g < 4; ++g)
        #pragma unroll
        for (int os = 0; os < 4; ++os) accY[g][os] = (f32x4){0.f, 0.f, 0.f, 0.f};
    f32x4 csacc[4];
    #pragma unroll
    for (int g = 0; g < 4; ++g) csacc[g] = (f32x4){0.f, 0.f, 0.f, 0.f};

    stage(n_start, 0);
    __syncthreads();

    for (int c = 0; c < n_chunks; ++c) {
        const int n0 = n_start + c * 64;
        const int p = c & 1;
        if (c + 1 < n_chunks) stage(n0 + 64, 1 - p);

        const unsigned short* qt = (const unsigned short*)(lds_raw + p * 8192);
        const unsigned short* vt = (const unsigned short*)(lds_raw + 16384 + p * 8192);

        // colsum weight fragment for this wave's 32-n slice (tiny L1 load)
        const bf16x8 wfrag = *(const bf16x8*)(wb + n0 + nh2 * 32 + quad * 8);

        // E phase over this wave's 32 n-rows; S' = exp2(E') straight to LDS
        #pragma unroll
        for (int ns = 0; ns < 2; ++ns) {
            const int row = nh2 * 32 + ns * 16 + col;
            const bf16x8 qa0 = *(const bf16x8*)(qt + row * 64 + ((quad ^ (col & 7)) * 8));
            const bf16x8 qa1 = *(const bf16x8*)(qt + row * 64 + (((4 + quad) ^ (col & 7)) * 8));
            #pragma unroll
            for (int g = 0; g < 4; ++g) {
                f32x4 acc = {0.f, 0.f, 0.f, 0.f};
                acc = MFMA16(qa0, kb0[g], acc);
                acc = MFMA16(qa1, kb1[g], acc);
                union { unsigned short us[4]; uint2 u2; } pk;
                #pragma unroll
                for (int r = 0; r < 4; ++r)
                    pk.us[r] = f2bf(__builtin_amdgcn_exp2f(acc[r]));
                *(uint2*)&stS[(g * 16 + col) * 40 + ns * 16 + quad * 4] = pk.u2;
            }
        }

        // same-wave round-trip: S' as B-operand (K = this wave's 32 n)
        bf16x8 sB[4];
        #pragma unroll
        for (int g = 0; g < 4; ++g)
            sB[g] = *(const bf16x8*)&stS[(g * 16 + col) * 40 + quad * 8];

        // colsum via MFMA: A rows all = w  ->  D rows all = colsum
        #pragma unroll
        for (int g = 0; g < 4; ++g)
            csacc[g] = MFMA16(wfrag, sB[g], csacc[g]);

        // PV: A = xv rows (o), k = this wave's 32 n
        #pragma unroll
        for (int os = 0; os < 4; ++os) {
            const bf16x8 va = *(const bf16x8*)(vt + (os * 16 + col) * 64 +
                                               (((nh2 * 4 + quad) ^ (col & 7)) * 8));
            #pragma unroll
            for (int g = 0; g < 4; ++g)
                accY[g][os] = MFMA16(va, sB[g], accY[g][os]);
        }
        __syncthreads();
    }

    // epilogue: combine the two n-halves (waves nh2=1 -> LDS; nh2=0 adds+writes)
    float* cmb = (float*)lds_raw;              // 32 KB: [mh][g*4+os][r][lane]
    float* csc = (float*)(lds_raw + 32768);    // 2 KB:  [mh][g][lane]
    if (nh2 == 1) {
        #pragma unroll
        for (int g = 0; g < 4; ++g) {
            #pragma unroll
            for (int os = 0; os < 4; ++os)
                #pragma unroll
                for (int r = 0; r < 4; ++r)
                    cmb[((mh * 16 + g * 4 + os) * 4 + r) * 64 + lane] = accY[g][os][r];
            csc[(mh * 4 + g) * 64 + lane] = csacc[g][0];
        }
    }
    __syncthreads();
    if (nh2 == 0) {
        #pragma unroll
        for (int g = 0; g < 4; ++g) {
            const float cs = csacc[g][0] + csc[(mh * 4 + g) * 64 + lane];
            if (lane < 16)
                cspart[((size_t)sk * 8 + b) * N_ + m_wave + g * 16 + lane] = cs;
            #pragma unroll
            for (int os = 0; os < 4; ++os)
                #pragma unroll
                for (int r = 0; r < 4; ++r) {
                    const float v = accY[g][os][r] +
                        cmb[((mh * 16 + g * 4 + os) * 4 + r) * 64 + lane];
                    yp[(size_t)(b * C2_ + os * 16 + quad * 4 + r) * N_ + m_wave + g * 16 + col] = v;
                }
        }
    }
}

// K3b: xr = (Y0+Y1+Y2) / (1e-9 + cs0+cs1+cs2), in-place over the Y0 region.
__global__ __launch_bounds__(256) void k3b_comb(
    float* yp0, const float* __restrict__ yp1, const float* __restrict__ yp2,
    const float* __restrict__ cspart)
{
    const int idx4 = blockIdx.x * 256 + threadIdx.x;  // [0, 524288) float4 idx
    const int b = idx4 >> 16;
    const int m4 = idx4 & 1023;
    const float4 y0 = ((const float4*)yp0)[idx4];
    const float4 y1 = ((const float4*)yp1)[idx4];
    const float4 y2 = ((const float4*)yp2)[idx4];
    const float4 c0 = ((const float4*)cspart)[b * 1024 + m4];
    const float4 c1 = ((const float4*)cspart)[8192 + b * 1024 + m4];
    const float4 c2 = ((const float4*)cspart)[16384 + b * 1024 + m4];
    float4 r;
    r.x = (y0.x + y1.x + y2.x) / (1e-9f + c0.x + c1.x + c2.x);
    r.y = (y0.y + y1.y + y2.y) / (1e-9f + c0.y + c1.y + c2.y);
    r.z = (y0.z + y1.z + y2.z) / (1e-9f + c0.z + c1.z + c2.z);
    r.w = (y0.w + y1.w + y2.w) / (1e-9f + c0.w + c1.w + c2.w);
    ((float4*)yp0)[idx4] = r;
}

// ---------------------------------------------------------------------------
// K4: t = w_t @ (xc - xr) + b_t, per (b, 64-n tile).  d-tile + w_t in LDS.
// ---------------------------------------------------------------------------
__global__ __launch_bounds__(256) void k4_t(
    const float* __restrict__ xc, const float* __restrict__ xr,
    const float* __restrict__ w_t, const float* __restrict__ b_t,
    float* __restrict__ t_buf)
{
    __shared__ float d_lds[64][64];
    __shared__ float w_lds[64][64];
    const int b = blockIdx.y;
    const int n0 = blockIdx.x * 64;
    const size_t base = (size_t)b * C2_ * N_;

    for (int idx = threadIdx.x; idx < 4096; idx += 256) {
        const int i = idx >> 6, n = idx & 63;
        const size_t g = base + (size_t)i * N_ + n0 + n;
        d_lds[i][n] = xc[g] - xr[g];
        w_lds[i][n] = w_t[idx];
    }
    __syncthreads();

    const int n = threadIdx.x & 63, ow = (threadIdx.x >> 6) * 16;
    float acc[16];
    #pragma unroll
    for (int oo = 0; oo < 16; ++oo) acc[oo] = 0.f;
    for (int i = 0; i < 64; ++i) {
        const float dv = d_lds[i][n];
        #pragma unroll
        for (int oo = 0; oo < 16; ++oo)
            acc[oo] += w_lds[ow + oo][i] * dv;
    }
    #pragma unroll
    for (int oo = 0; oo < 16; ++oo)
        t_buf[base + (size_t)(ow + oo) * N_ + n0 + n] = acc[oo] + b_t[ow + oo];
}

// ---------------------------------------------------------------------------
// K5: BN batch stats per channel (sum, sumsq over B*N).  One block per o.
// ---------------------------------------------------------------------------
__global__ __launch_bounds__(256) void k5_bnstats(
    const float* __restrict__ t_buf, float* __restrict__ bn)
{
    const int o = blockIdx.x;
    float s = 0.f, s2 = 0.f;
    for (int b = 0; b < B_; ++b) {
        const float4* p = (const float4*)(t_buf + (size_t)(b * C2_ + o) * N_);
        for (int j = threadIdx.x; j < N_ / 4; j += 256) {
            const float4 v = p[j];
            s  += v.x + v.y + v.z + v.w;
            s2 += v.x * v.x + v.y * v.y + v.z * v.z + v.w * v.w;
        }
    }
    #pragma unroll
    for (int off = 1; off < 64; off <<= 1) {
        s  += __shfl_xor(s, off, 64);
        s2 += __shfl_xor(s2, off, 64);
    }
    __shared__ float red[2][4];
    if ((threadIdx.x & 63) == 0) {
        red[0][threadIdx.x >> 6] = s;
        red[1][threadIdx.x >> 6] = s2;
    }
    __syncthreads();
    if (threadIdx.x == 0) {
        bn[o]       = red[0][0] + red[0][1] + red[0][2] + red[0][3];
        bn[64 + o]  = red[1][0] + red[1][1] + red[1][2] + red[1][3];
    }
}

// ---------------------------------------------------------------------------
// K6: out = xc + relu(gamma * (t - mean) * rsqrt(var + eps) + beta)
// ---------------------------------------------------------------------------
__global__ __launch_bounds__(256) void k6_out(
    const float* __restrict__ xc, const float* __restrict__ t_buf,
    const float* __restrict__ bn, const float* __restrict__ gamma,
    const float* __restrict__ beta, float* __restrict__ out)
{
    const int idx = blockIdx.x * 256 + threadIdx.x;
    const int o = (idx >> 10) & 63;
    const float invC = 1.0f / (float)(B_ * N_);
    const float mean = bn[o] * invC;
    const float var  = bn[64 + o] * invC - mean * mean;
    const float sc = gamma[o] * rsqrtf(var + 1e-5f);
    const float sh = beta[o] - mean * sc;
    const float4 t4 = ((const float4*)t_buf)[idx];
    const float4 c4 = ((const float4*)xc)[idx];
    float4 r;
    r.x = c4.x + fmaxf(0.f, sc * t4.x + sh);
    r.y = c4.y + fmaxf(0.f, sc * t4.y + sh);
    r.z = c4.z + fmaxf(0.f, sc * t4.z + sh);
    r.w = c4.w + fmaxf(0.f, sc * t4.w + sh);
    ((float4*)out)[idx] = r;
}

extern "C" void kernel_launch(void* const* d_in, const int* in_sizes, int n_in,
                              void* d_out, int out_size, void* d_ws, size_t ws_size,
                              hipStream_t stream) {
    const float* x     = (const float*)d_in[0];
    const float* w_qk  = (const float*)d_in[1];
    const float* w_v   = (const float*)d_in[2];
    const float* b_v   = (const float*)d_in[3];
    const float* w_x   = (const float*)d_in[4];
    const float* w_t   = (const float*)d_in[5];
    const float* b_t   = (const float*)d_in[6];
    const float* gamma = (const float*)d_in[7];
    const float* beta  = (const float*)d_in[8];
    float* out = (float*)d_out;

    char* ws = (char*)d_ws;
    unsigned short* qk_t  = (unsigned short*)ws;                      // 4 MB
    unsigned short* xv_bf = (unsigned short*)(ws + (4  << 20));       // 4 MB
    float* xc      = (float*)(ws + (8  << 20));                       // 8 MB
    float* xr_yp0  = (float*)(ws + (16 << 20));                       // 8 MB (ypart0 -> xr in place)
    float* tb_yp1  = (float*)(ws + (24 << 20));                       // 8 MB (ypart1, then t_buf)
    float* part_rs = (float*)(ws + (32 << 20));                       // 1 MB (k2 -> k2b)
    float* cspart  = (float*)(ws + (32 << 20));                       // 384 KB (k3 -> k3b; reuses part_rs)
    float* winv    = (float*)(ws + (33 << 20));                       // 128 KB
    unsigned short* wbf = (unsigned short*)(ws + (33 << 20) + (128 << 10)); // 64 KB
    float* bn      = (float*)(ws + (33 << 20) + (192 << 10));         // 512 B
    float* yp2     = out;                                             // 8 MB scratch until k3b

    hipLaunchKernelGGL(k1_proj,     dim3(64, 8),  256, 0, stream,
                       x, w_qk, w_v, b_v, w_x, qk_t, xv_bf, xc);
    hipLaunchKernelGGL(k2_rowstats, dim3(1024),   256, 0, stream, qk_t, part_rs);
    hipLaunchKernelGGL(k2b_comb,    dim3(128),    256, 0, stream, part_rs, winv, wbf);
    hipLaunchKernelGGL(k2c_scale,   dim3(2048),   256, 0, stream, xv_bf, winv);
    hipLaunchKernelGGL(k3_pv,       dim3(768),    256, 0, stream,
                       qk_t, xv_bf, wbf, xr_yp0, tb_yp1, yp2, cspart);
    hipLaunchKernelGGL(k3b_comb,    dim3(2048),   256, 0, stream, xr_yp0, tb_yp1, yp2, cspart);
    hipLaunchKernelGGL(k4_t,        dim3(64, 8),  256, 0, stream, xc, xr_yp0, w_t, b_t, tb_yp1);
    hipLaunchKernelGGL(k5_bnstats,  dim3(64),     256, 0, stream, tb_yp1, bn);
    hipLaunchKernelGGL(k6_out,      dim3(2048),   256, 0, stream, xc, tb_yp1, bn, gamma, beta, out);
}

// Round 9
// 168.903 us; speedup vs baseline: 3.0660x; 1.1409x over previous
//
#include <hip/hip_runtime.h>

#define B_   8
#define C_   128
#define N_   4096
#define C2_  64

typedef __bf16 bf16x8 __attribute__((ext_vector_type(8)));
typedef float  f32x4  __attribute__((ext_vector_type(4)));

#define MFMA16(a, b, c) __builtin_amdgcn_mfma_f32_16x16x32_bf16((a), (b), (c), 0, 0, 0)

// sqrt(log2(e)): fold into q/k so softmax uses exp2 directly (E' = E * log2e)
#define QK_SCALE 1.2011224087864498f

static __device__ __forceinline__ unsigned short f2bf(float f) {
    union { __bf16 b; unsigned short u; } cv;
    cv.b = (__bf16)f;
    return cv.u;
}
static __device__ __forceinline__ float bf2f(unsigned short u) {
    union { unsigned int u; float f; } cv;
    cv.u = ((unsigned int)u) << 16;
    return cv.f;
}

struct us4 { unsigned short a, b, c, d; };

// async global->LDS, 16 B per lane.  LDS dest must be linear in lane order.
static __device__ __forceinline__ void gl_lds16(const unsigned short* g, void* l) {
    __builtin_amdgcn_global_load_lds(
        (const __attribute__((address_space(1))) unsigned int*)g,
        (__attribute__((address_space(3))) unsigned int*)l,
        16, 0, 0);
}

// ---------------------------------------------------------------------------
// K1: fused projection GEMM.  D[192 o][64 n] = W(3x64 stacked)[o][c] * x[c][n]
//     per (b, 64-n tile).  Weights -> LDS bf16 [192][136]; x tile transposed
//     -> LDS bf16 x_t[64 n][136 c].  Epilogue: ot 0-3 -> qk_t (us4, *QK_SCALE);
//     ot 4-7 -> xv_bf (+b_v); ot 8-11 -> xc (f32).
// ---------------------------------------------------------------------------
__global__ __launch_bounds__(256) void k1_proj(
    const float* __restrict__ x, const float* __restrict__ w_qk,
    const float* __restrict__ w_v, const float* __restrict__ b_v,
    const float* __restrict__ w_x,
    unsigned short* __restrict__ qk_t, unsigned short* __restrict__ xv_bf,
    float* __restrict__ xc)
{
    __shared__ __align__(16) unsigned short w_lds[192 * 136];
    __shared__ __align__(16) unsigned short x_t[64 * 136];
    const int tid = threadIdx.x;
    const int wave = tid >> 6, lane = tid & 63;
    const int quad = lane >> 4, col = lane & 15;
    const int b = blockIdx.y;
    const int n0 = blockIdx.x * 64;

    const float* wsrc[3] = {w_qk, w_v, w_x};
    #pragma unroll
    for (int mat = 0; mat < 3; ++mat) {
        const float* wm = wsrc[mat];
        #pragma unroll
        for (int it = 0; it < 8; ++it) {
            const int idx = it * 256 + tid;            // [0, 2048)
            const int o = idx >> 5, c = (idx & 31) * 4;
            const float4 v = *(const float4*)(wm + o * C_ + c);
            us4 pk;
            pk.a = f2bf(v.x); pk.b = f2bf(v.y); pk.c = f2bf(v.z); pk.d = f2bf(v.w);
            *(us4*)&w_lds[(mat * 64 + o) * 136 + c] = pk;
        }
    }
    const float* xb = x + (size_t)b * C_ * N_ + n0;
    #pragma unroll
    for (int it = 0; it < 8; ++it) {
        const int idx = it * 256 + tid;                // [0, 2048)
        const int c = idx >> 4, n = (idx & 15) * 4;
        const float4 v = *(const float4*)(xb + (size_t)c * N_ + n);
        x_t[(n + 0) * 136 + c] = f2bf(v.x);
        x_t[(n + 1) * 136 + c] = f2bf(v.y);
        x_t[(n + 2) * 136 + c] = f2bf(v.z);
        x_t[(n + 3) * 136 + c] = f2bf(v.w);
    }
    __syncthreads();

    const int nw = wave * 16;
    bf16x8 bfr[4];
    #pragma unroll
    for (int kt = 0; kt < 4; ++kt)
        bfr[kt] = *(const bf16x8*)&x_t[(nw + col) * 136 + kt * 32 + quad * 8];

    const int n_g = n0 + nw + col;

    #pragma unroll
    for (int ot = 0; ot < 12; ++ot) {
        f32x4 acc = {0.f, 0.f, 0.f, 0.f};
        #pragma unroll
        for (int kt = 0; kt < 4; ++kt) {
            const bf16x8 afr = *(const bf16x8*)&w_lds[(ot * 16 + col) * 136 + kt * 32 + quad * 8];
            acc = MFMA16(afr, bfr[kt], acc);
        }
        if (ot < 4) {
            us4 pk;
            pk.a = f2bf(acc[0] * QK_SCALE); pk.b = f2bf(acc[1] * QK_SCALE);
            pk.c = f2bf(acc[2] * QK_SCALE); pk.d = f2bf(acc[3] * QK_SCALE);
            *(us4*)&qk_t[(size_t)(b * N_ + n_g) * C2_ + ot * 16 + quad * 4] = pk;
        } else if (ot < 8) {
            const float4 bv4 = *(const float4*)(b_v + (ot - 4) * 16 + quad * 4);
            const float* bvp = (const float*)&bv4;
            #pragma unroll
            for (int r = 0; r < 4; ++r)
                xv_bf[(size_t)(b * C2_ + (ot - 4) * 16 + quad * 4 + r) * N_ + n_g]
                    = f2bf(acc[r] + bvp[r]);
        } else {
            #pragma unroll
            for (int r = 0; r < 4; ++r)
                xc[(size_t)(b * C2_ + (ot - 8) * 16 + quad * 4 + r) * N_ + n_g] = acc[r];
        }
    }
}

// ---------------------------------------------------------------------------
// K2: partial row softmax sums.  Grid 1024: b=id&7, nblk=(id>>3)&15, mq=id>>7.
//     Wave owns 64 n-rows (4 A-frag sets); block owns 256 rows x 512 m as
//     4 chunks of 128 m (32 KB dbuf; half the barriers of 64-m chunks).
//     Writes part_rs[mq][b][n].  4 blocks/CU.
// ---------------------------------------------------------------------------
__global__ __launch_bounds__(256) void k2_rowstats(
    const unsigned short* __restrict__ qk_t, float* __restrict__ part_rs)
{
    __shared__ __align__(16) unsigned char lds_raw[2 * 16384];
    const int tid = threadIdx.x;
    const int wave = tid >> 6, lane = tid & 63;
    const int quad = lane >> 4, col = lane & 15;
    const int b = blockIdx.x & 7;
    const int nblk = (blockIdx.x >> 3) & 15;
    const int mq = blockIdx.x >> 7;                   // 0..7
    const int n_base = nblk * 256 + wave * 64;
    const int m_start = mq * 512;
    const unsigned short* qb = qk_t + (size_t)b * N_ * C2_;

    // four persistent A-frag sets: rows n_base + s*16 + col
    bf16x8 a0[4], a1[4];
    #pragma unroll
    for (int s = 0; s < 4; ++s) {
        const unsigned short* p = qb + (size_t)(n_base + s * 16 + col) * C2_ + quad * 8;
        a0[s] = *(const bf16x8*)p;
        a1[s] = *(const bf16x8*)(p + 32);
    }

    // stage 128 m-rows (16 KB) into buffer p
    auto stage = [&](int m0, int p) {
        unsigned char* base = lds_raw + p * 16384;
        #pragma unroll
        for (int r = 0; r < 4; ++r) {
            const int idx = r * 256 + tid;             // [0, 1024)
            const int row = idx >> 3, seg = idx & 7;
            gl_lds16(qb + (size_t)(m0 + row) * C2_ + (size_t)(seg ^ (row & 7)) * 8,
                     base + idx * 16);
        }
    };

    float run_s[4][4];
    #pragma unroll
    for (int s = 0; s < 4; ++s)
        #pragma unroll
        for (int r = 0; r < 4; ++r) run_s[s][r] = 0.f;

    stage(m_start, 0);
    __syncthreads();

    for (int c = 0; c < 4; ++c) {
        const int p = c & 1;
        if (c + 1 < 4) stage(m_start + (c + 1) * 128, 1 - p);
        const unsigned short* qt = (const unsigned short*)(lds_raw + p * 16384);
        #pragma unroll
        for (int ms = 0; ms < 8; ++ms) {
            const int row = ms * 16 + col;
            const bf16x8 b0 = *(const bf16x8*)(qt + row * 64 + ((quad ^ (col & 7)) * 8));
            const bf16x8 b1 = *(const bf16x8*)(qt + row * 64 + (((4 + quad) ^ (col & 7)) * 8));
            #pragma unroll
            for (int s = 0; s < 4; ++s) {
                f32x4 acc = {0.f, 0.f, 0.f, 0.f};
                acc = MFMA16(a0[s], b0, acc);
                acc = MFMA16(a1[s], b1, acc);
                #pragma unroll
                for (int r = 0; r < 4; ++r)
                    run_s[s][r] += __builtin_amdgcn_exp2f(acc[r]);
            }
        }
        __syncthreads();
    }

    #pragma unroll
    for (int s = 0; s < 4; ++s)
        #pragma unroll
        for (int r = 0; r < 4; ++r) {
            #pragma unroll
            for (int off = 1; off < 16; off <<= 1)
                run_s[s][r] += __shfl_xor(run_s[s][r], off, 64);
        }
    if (col == 0) {
        #pragma unroll
        for (int s = 0; s < 4; ++s)
            #pragma unroll
            for (int r = 0; r < 4; ++r)
                part_rs[((size_t)(mq * 8 + b) << 12) + n_base + s * 16 + quad * 4 + r]
                    = run_s[s][r];
    }
}

// ---------------------------------------------------------------------------
// K2bc: fused rowsum-combine + xv scale.  Grid 512: b=id&7, nt=id>>3.
//       winv = 1/rowsum (LDS-local); wbf = bf16(winv); xv *= winv in place.
// ---------------------------------------------------------------------------
__global__ __launch_bounds__(256) void k2bc(
    const float* __restrict__ part_rs, unsigned short* __restrict__ xv_bf,
    unsigned short* __restrict__ wbf)
{
    __shared__ float wl[64];
    const int tid = threadIdx.x;
    const int b = blockIdx.x & 7;
    const int n0 = (blockIdx.x >> 3) * 64;
    if (tid < 64) {
        float s = 0.f;
        #pragma unroll
        for (int q = 0; q < 8; ++q)
            s += part_rs[((size_t)(q * 8 + b) << 12) + n0 + tid];
        const float w = 1.0f / s;
        wl[tid] = w;
        wbf[b * N_ + n0 + tid] = f2bf(w);
    }
    __syncthreads();
    #pragma unroll
    for (int it = 0; it < 4; ++it) {
        const int idx4 = it * 256 + tid;               // [0, 1024)
        const int o = idx4 >> 4, n4 = (idx4 & 15) * 4;
        unsigned short* p = xv_bf + (size_t)(b * C2_ + o) * N_ + n0 + n4;
        us4 v = *(us4*)p;
        v.a = f2bf(bf2f(v.a) * wl[n4 + 0]);
        v.b = f2bf(bf2f(v.b) * wl[n4 + 1]);
        v.c = f2bf(bf2f(v.c) * wl[n4 + 2]);
        v.d = f2bf(bf2f(v.d) * wl[n4 + 3]);
        *(us4*)p = v;
    }
}

// ---------------------------------------------------------------------------
// K3: block owns 128 m-cols and a THIRD of n (split-K, grid 768, 3 blk/CU).
//     Waves: (m-half mh, n-half nh2).  Per 64-n chunk: stage qk slab + xv tile
//     (dbuf DMA); each wave computes E for its 32 n x 64 m; S' = exp2(E)
//     (row-normalizer pre-folded into xv); LDS round-trip; PV MFMA + colsum
//     MFMA (A-rows = wbf).  Epilogue: cross n-half combine in LDS; write
//     partial Y + partial colsum; k4 combines the 3 splits.
// ---------------------------------------------------------------------------
__global__ __launch_bounds__(256, 3) void k3_pv(
    const unsigned short* __restrict__ qk_t, const unsigned short* __restrict__ xv_bf,
    const unsigned short* __restrict__ wbf,
    float* __restrict__ yp0, float* __restrict__ yp1, float* __restrict__ yp2,
    float* __restrict__ cspart)
{
    // 0..16K: qk dbuf | 16K..32K: xv dbuf | 32K..52K: S tiles (4 waves x [4g][16][40])
    __shared__ __align__(16) unsigned char lds_raw[32768 + 4 * 5120];
    const int tid = threadIdx.x;
    const int wave = tid >> 6, lane = tid & 63;
    const int quad = lane >> 4, col = lane & 15;
    const int nh2 = wave & 1, mh = wave >> 1;
    const int b = blockIdx.x & 7;
    const int m_blk = ((blockIdx.x >> 3) & 31) * 128;
    const int sk = blockIdx.x >> 8;                  // 0..2 (split-K index)
    const int n_start = (sk == 0) ? 0 : 1408 + (sk - 1) * 1344;
    const int n_chunks = (sk == 0) ? 22 : 21;
    const int m_wave = m_blk + mh * 64;
    const unsigned short* qb = qk_t + (size_t)b * N_ * C2_;
    const unsigned short* vb = xv_bf + (size_t)b * C2_ * N_;
    const unsigned short* wb = wbf + b * N_;
    float* yp = (sk == 0) ? yp0 : (sk == 1) ? yp1 : yp2;

    // persistent B-operands for E: this wave's 64 m-cols (4 groups of 16)
    bf16x8 kb0[4], kb1[4];
    #pragma unroll
    for (int g = 0; g < 4; ++g) {
        const unsigned short* p = qb + (size_t)(m_wave + g * 16 + col) * C2_ + quad * 8;
        kb0[g] = *(const bf16x8*)p;
        kb1[g] = *(const bf16x8*)(p + 32);
    }

    unsigned short* stS = (unsigned short*)(lds_raw + 32768 + wave * 5120); // [g][col][40]

    auto stage = [&](int n0, int p) {
        unsigned char* qbase = lds_raw + p * 8192;
        unsigned char* vbase = lds_raw + 16384 + p * 8192;
        #pragma unroll
        for (int r = 0; r < 2; ++r) {
            const int idx = r * 256 + tid;
            const int row = idx >> 3, seg = idx & 7;
            const int ss = seg ^ (row & 7);
            gl_lds16(qb + (size_t)(n0 + row) * C2_ + (size_t)ss * 8, qbase + idx * 16);
            gl_lds16(vb + (size_t)row * N_ + n0 + ss * 8, vbase + idx * 16);
        }
    };

    f32x4 accY[4][4];
    #pragma unroll
    for (int g = 0; g < 4; ++g)
        #pragma unroll
        for (int os = 0; os < 4; ++os) accY[g][os] = (f32x4){0.f, 0.f, 0.f, 0.f};
    f32x4 csacc[4];
    #pragma unroll
    for (int g = 0; g < 4; ++g) csacc[g] = (f32x4){0.f, 0.f, 0.f, 0.f};

    stage(n_start, 0);
    __syncthreads();

    for (int c = 0; c < n_chunks; ++c) {
        const int n0 = n_start + c * 64;
        const int p = c & 1;
        if (c + 1 < n_chunks) stage(n0 + 64, 1 - p);

        const unsigned short* qt = (const unsigned short*)(lds_raw + p * 8192);
        const unsigned short* vt = (const unsigned short*)(lds_raw + 16384 + p * 8192);

        // colsum weight fragment for this wave's 32-n slice (tiny L1 load)
        const bf16x8 wfrag = *(const bf16x8*)(wb + n0 + nh2 * 32 + quad * 8);

        // E phase over this wave's 32 n-rows; S' = exp2(E') straight to LDS
        #pragma unroll
        for (int ns = 0; ns < 2; ++ns) {
            const int row = nh2 * 32 + ns * 16 + col;
            const bf16x8 qa0 = *(const bf16x8*)(qt + row * 64 + ((quad ^ (col & 7)) * 8));
            const bf16x8 qa1 = *(const bf16x8*)(qt + row * 64 + (((4 + quad) ^ (col & 7)) * 8));
            #pragma unroll
            for (int g = 0; g < 4; ++g) {
                f32x4 acc = {0.f, 0.f, 0.f, 0.f};
                acc = MFMA16(qa0, kb0[g], acc);
                acc = MFMA16(qa1, kb1[g], acc);
                union { unsigned short us[4]; uint2 u2; } pk;
                #pragma unroll
                for (int r = 0; r < 4; ++r)
                    pk.us[r] = f2bf(__builtin_amdgcn_exp2f(acc[r]));
                *(uint2*)&stS[(g * 16 + col) * 40 + ns * 16 + quad * 4] = pk.u2;
            }
        }

        // same-wave round-trip: S' as B-operand (K = this wave's 32 n)
        bf16x8 sB[4];
        #pragma unroll
        for (int g = 0; g < 4; ++g)
            sB[g] = *(const bf16x8*)&stS[(g * 16 + col) * 40 + quad * 8];

        // colsum via MFMA: A rows all = w  ->  D rows all = colsum
        #pragma unroll
        for (int g = 0; g < 4; ++g)
            csacc[g] = MFMA16(wfrag, sB[g], csacc[g]);

        // PV: A = xv rows (o), k = this wave's 32 n
        #pragma unroll
        for (int os = 0; os < 4; ++os) {
            const bf16x8 va = *(const bf16x8*)(vt + (os * 16 + col) * 64 +
                                               (((nh2 * 4 + quad) ^ (col & 7)) * 8));
            #pragma unroll
            for (int g = 0; g < 4; ++g)
                accY[g][os] = MFMA16(va, sB[g], accY[g][os]);
        }
        __syncthreads();
    }

    // epilogue: combine the two n-halves (waves nh2=1 -> LDS; nh2=0 adds+writes)
    float* cmb = (float*)lds_raw;              // 32 KB: [mh][g*4+os][r][lane]
    float* csc = (float*)(lds_raw + 32768);    // 2 KB:  [mh][g][lane]
    if (nh2 == 1) {
        #pragma unroll
        for (int g = 0; g < 4; ++g) {
            #pragma unroll
            for (int os = 0; os < 4; ++os)
                #pragma unroll
                for (int r = 0; r < 4; ++r)
                    cmb[((mh * 16 + g * 4 + os) * 4 + r) * 64 + lane] = accY[g][os][r];
            csc[(mh * 4 + g) * 64 + lane] = csacc[g][0];
        }
    }
    __syncthreads();
    if (nh2 == 0) {
        #pragma unroll
        for (int g = 0; g < 4; ++g) {
            const float cs = csacc[g][0] + csc[(mh * 4 + g) * 64 + lane];
            if (lane < 16)
                cspart[((size_t)sk * 8 + b) * N_ + m_wave + g * 16 + lane] = cs;
            #pragma unroll
            for (int os = 0; os < 4; ++os)
                #pragma unroll
                for (int r = 0; r < 4; ++r) {
                    const float v = accY[g][os][r] +
                        cmb[((mh * 16 + g * 4 + os) * 4 + r) * 64 + lane];
                    yp[(size_t)(b * C2_ + os * 16 + quad * 4 + r) * N_ + m_wave + g * 16 + col] = v;
                }
        }
    }
}

// ---------------------------------------------------------------------------
// K4: fused partial-combine + w_t GEMM (MFMA) + BN partial stats.
//     Per (b, 64-n tile): cinv = 1/(eps+sum cspart); d = xc - (y0+y1+y2)*cinv
//     staged TRANSPOSED to LDS bf16 d_t[n][72]; w_t staged bf16 [o][72].
//     Wave = o-tile; K = 64 -> kt in [0,2).  t = acc + b_t -> t_buf;
//     per-block channel partial sums/sumsq -> part_bn[c][blk].
//     NOTE: reads y1 region == writes t_buf region; all reads complete
//     before the post-staging barrier, writes only after (same tile only).
// ---------------------------------------------------------------------------
__global__ __launch_bounds__(256) void k4_t(
    const float* __restrict__ xc, const float* __restrict__ y0,
    const float* __restrict__ y1, const float* __restrict__ y2,
    const float* __restrict__ cspart, const float* __restrict__ w_t,
    const float* __restrict__ b_t, float* __restrict__ t_buf,
    float* __restrict__ part_bn)
{
    __shared__ __align__(16) unsigned short wlds[64 * 72];
    __shared__ __align__(16) unsigned short d_t[64 * 72];
    __shared__ float cinv[64];
    const int tid = threadIdx.x;
    const int wave = tid >> 6, lane = tid & 63;
    const int quad = lane >> 4, col = lane & 15;
    const int b = blockIdx.y;
    const int n0 = blockIdx.x * 64;
    const size_t base = (size_t)b * C2_ * N_;

    // phase 0: w_t -> bf16 LDS; per-n colsum inverse
    #pragma unroll
    for (int it = 0; it < 4; ++it) {
        const int idx4 = it * 256 + tid;               // [0, 1024)
        const int o = idx4 >> 4, i4 = (idx4 & 15) * 4;
        const float4 v = *(const float4*)(w_t + o * 64 + i4);
        us4 pk;
        pk.a = f2bf(v.x); pk.b = f2bf(v.y); pk.c = f2bf(v.z); pk.d = f2bf(v.w);
        *(us4*)&wlds[o * 72 + i4] = pk;
    }
    if (tid < 64) {
        const int n = n0 + tid;
        const float cs = cspart[(size_t)b * N_ + n] + cspart[(size_t)(8 + b) * N_ + n]
                       + cspart[(size_t)(16 + b) * N_ + n];
        cinv[tid] = 1.0f / (1e-9f + cs);
    }
    __syncthreads();

    // phase 1: d = xc - (y0+y1+y2)*cinv, transposed bf16 -> d_t[n][i]
    #pragma unroll
    for (int it = 0; it < 4; ++it) {
        const int idx4 = it * 256 + tid;               // [0, 1024)
        const int i = idx4 >> 4, n4 = (idx4 & 15) * 4;
        const size_t g = base + (size_t)i * N_ + n0 + n4;
        const float4 c4 = *(const float4*)(xc + g);
        const float4 a0 = *(const float4*)(y0 + g);
        const float4 a1 = *(const float4*)(y1 + g);
        const float4 a2 = *(const float4*)(y2 + g);
        d_t[(n4 + 0) * 72 + i] = f2bf(c4.x - (a0.x + a1.x + a2.x) * cinv[n4 + 0]);
        d_t[(n4 + 1) * 72 + i] = f2bf(c4.y - (a0.y + a1.y + a2.y) * cinv[n4 + 1]);
        d_t[(n4 + 2) * 72 + i] = f2bf(c4.z - (a0.z + a1.z + a2.z) * cinv[n4 + 2]);
        d_t[(n4 + 3) * 72 + i] = f2bf(c4.w - (a0.w + a1.w + a2.w) * cinv[n4 + 3]);
    }
    __syncthreads();

    const int ow = wave * 16;
    bf16x8 afr[2];
    #pragma unroll
    for (int kt = 0; kt < 2; ++kt)
        afr[kt] = *(const bf16x8*)&wlds[(ow + col) * 72 + kt * 32 + quad * 8];
    const float4 bt4 = *(const float4*)(b_t + ow + quad * 4);
    const float* btp = (const float*)&bt4;

    float s[4] = {0.f, 0.f, 0.f, 0.f}, q2[4] = {0.f, 0.f, 0.f, 0.f};
    #pragma unroll
    for (int ns = 0; ns < 4; ++ns) {
        f32x4 acc = {0.f, 0.f, 0.f, 0.f};
        #pragma unroll
        for (int kt = 0; kt < 2; ++kt) {
            const bf16x8 bfr = *(const bf16x8*)&d_t[(ns * 16 + col) * 72 + kt * 32 + quad * 8];
            acc = MFMA16(afr[kt], bfr, acc);
        }
        #pragma unroll
        for (int r = 0; r < 4; ++r) {
            const float t = acc[r] + btp[r];
            t_buf[base + (size_t)(ow + quad * 4 + r) * N_ + n0 + ns * 16 + col] = t;
            s[r] += t;
            q2[r] += t * t;
        }
    }
    #pragma unroll
    for (int r = 0; r < 4; ++r) {
        #pragma unroll
        for (int off = 1; off < 16; off <<= 1) {
            s[r]  += __shfl_xor(s[r],  off, 64);
            q2[r] += __shfl_xor(q2[r], off, 64);
        }
    }
    if (col == 0) {
        const int blk = blockIdx.x * 8 + b;            // [0, 512)
        #pragma unroll
        for (int r = 0; r < 4; ++r) {
            part_bn[(size_t)(ow + quad * 4 + r) * 512 + blk]      = s[r];
            part_bn[(size_t)(64 + ow + quad * 4 + r) * 512 + blk] = q2[r];
        }
    }
}

// K5r: bn[c] = sum_blk part_bn[c][blk], c in [0,128)
__global__ __launch_bounds__(256) void k5r(
    const float* __restrict__ part_bn, float* __restrict__ bn)
{
    const int c = blockIdx.x;
    const int tid = threadIdx.x, wave = tid >> 6, lane = tid & 63;
    float s = 0.f;
    for (int j = tid; j < 512; j += 256) s += part_bn[(size_t)c * 512 + j];
    #pragma unroll
    for (int off = 1; off < 64; off <<= 1) s += __shfl_xor(s, off, 64);
    __shared__ float red[4];
    if (lane == 0) red[wave] = s;
    __syncthreads();
    if (tid == 0) bn[c] = red[0] + red[1] + red[2] + red[3];
}

// ---------------------------------------------------------------------------
// K6: out = xc + relu(gamma * (t - mean) * rsqrt(var + eps) + beta)
// ---------------------------------------------------------------------------
__global__ __launch_bounds__(256) void k6_out(
    const float* __restrict__ xc, const float* __restrict__ t_buf,
    const float* __restrict__ bn, const float* __restrict__ gamma,
    const float* __restrict__ beta, float* __restrict__ out)
{
    const int idx = blockIdx.x * 256 + threadIdx.x;
    const int o = (idx >> 10) & 63;
    const float invC = 1.0f / (float)(B_ * N_);
    const float mean = bn[o] * invC;
    const float var  = bn[64 + o] * invC - mean * mean;
    const float sc = gamma[o] * rsqrtf(var + 1e-5f);
    const float sh = beta[o] - mean * sc;
    const float4 t4 = ((const float4*)t_buf)[idx];
    const float4 c4 = ((const float4*)xc)[idx];
    float4 r;
    r.x = c4.x + fmaxf(0.f, sc * t4.x + sh);
    r.y = c4.y + fmaxf(0.f, sc * t4.y + sh);
    r.z = c4.z + fmaxf(0.f, sc * t4.z + sh);
    r.w = c4.w + fmaxf(0.f, sc * t4.w + sh);
    ((float4*)out)[idx] = r;
}

extern "C" void kernel_launch(void* const* d_in, const int* in_sizes, int n_in,
                              void* d_out, int out_size, void* d_ws, size_t ws_size,
                              hipStream_t stream) {
    const float* x     = (const float*)d_in[0];
    const float* w_qk  = (const float*)d_in[1];
    const float* w_v   = (const float*)d_in[2];
    const float* b_v   = (const float*)d_in[3];
    const float* w_x   = (const float*)d_in[4];
    const float* w_t   = (const float*)d_in[5];
    const float* b_t   = (const float*)d_in[6];
    const float* gamma = (const float*)d_in[7];
    const float* beta  = (const float*)d_in[8];
    float* out = (float*)d_out;

    char* ws = (char*)d_ws;
    unsigned short* qk_t  = (unsigned short*)ws;                      // 4 MB
    unsigned short* xv_bf = (unsigned short*)(ws + (4  << 20));       // 4 MB
    float* xc      = (float*)(ws + (8  << 20));                       // 8 MB
    float* yp0     = (float*)(ws + (16 << 20));                       // 8 MB
    float* tb_yp1  = (float*)(ws + (24 << 20));                       // 8 MB (ypart1, then t_buf)
    float* part_rs = (float*)(ws + (32 << 20));                       // 1 MB (k2 -> k2bc)
    float* cspart  = (float*)(ws + (32 << 20));                       // 384 KB (k3 -> k4; reuses part_rs)
    unsigned short* wbf = (unsigned short*)(ws + (33 << 20));         // 64 KB
    float* part_bn = (float*)(ws + (33 << 20) + (64 << 10));          // 256 KB
    float* bn      = (float*)(ws + (33 << 20) + (320 << 10));         // 512 B
    float* yp2     = out;                                             // 8 MB scratch until k4

    hipLaunchKernelGGL(k1_proj,     dim3(64, 8),  256, 0, stream,
                       x, w_qk, w_v, b_v, w_x, qk_t, xv_bf, xc);
    hipLaunchKernelGGL(k2_rowstats, dim3(1024),   256, 0, stream, qk_t, part_rs);
    hipLaunchKernelGGL(k2bc,        dim3(512),    256, 0, stream, part_rs, xv_bf, wbf);
    hipLaunchKernelGGL(k3_pv,       dim3(768),    256, 0, stream,
                       qk_t, xv_bf, wbf, yp0, tb_yp1, yp2, cspart);
    hipLaunchKernelGGL(k4_t,        dim3(64, 8),  256, 0, stream,
                       xc, yp0, tb_yp1, yp2, cspart, w_t, b_t, tb_yp1, part_bn);
    hipLaunchKernelGGL(k5r,         dim3(128),    256, 0, stream, part_bn, bn);
    hipLaunchKernelGGL(k6_out,      dim3(2048),   256, 0, stream, xc, tb_yp1, bn, gamma, beta, out);
}